// Round 1
// baseline (4812.650 us; speedup 1.0000x reference)
//
#include <hip/hip_runtime.h>

#define EPS_BN 1e-5f

// ---------------------------------------------------------------- counts
__global__ void count_kernel(const int* __restrict__ dst, int E, float* __restrict__ cnt)
{
    for (int e = blockIdx.x * blockDim.x + threadIdx.x; e < E; e += gridDim.x * blockDim.x)
        atomicAdd(&cnt[dst[e]], 1.0f);
}

__global__ void invert_kernel(float* __restrict__ cnt, int n)
{
    for (int i = blockIdx.x * blockDim.x + threadIdx.x; i < n; i += gridDim.x * blockDim.x)
        cnt[i] = 1.0f / fmaxf(cnt[i], 1.0f);
}

// ---------------------------------------------------------------- combined root weights per dst type
// types: 0 drug {rels 4,5}, 1 protein {1,6}, 2 side_effect {0,3}, 3 pathway {2}
__global__ void wsum_kernel(const float* __restrict__ Wr, const float* __restrict__ br,
                            float* __restrict__ wsum, float* __restrict__ bsum, int K)
{
    const int nrel[4]  = {2, 2, 2, 1};
    const int rl[4][2] = {{4,5},{1,6},{0,3},{2,2}};
    int per = K * 256;
    for (int idx = blockIdx.x * blockDim.x + threadIdx.x; idx < 4 * per;
         idx += gridDim.x * blockDim.x) {
        int t = idx / per, o = idx - t * per;
        float s = Wr[rl[t][0] * per + o];
        if (nrel[t] > 1) s += Wr[rl[t][1] * per + o];
        wsum[idx] = s;
        if (idx < 4 * 256) {
            int tt = idx >> 8, oo = idx & 255;
            float sb = br[rl[tt][0] * 256 + oo];
            if (nrel[tt] > 1) sb += br[rl[tt][1] * 256 + oo];
            bsum[idx] = sb;
        }
    }
}

// ---------------------------------------------------------------- edge scatter-add (mean numerator)
__global__ void scatter_kernel(const int* __restrict__ src, const int* __restrict__ dst, int E,
                               const float* __restrict__ X, float* __restrict__ agg, int D)
{
    int gtid = blockIdx.x * blockDim.x + threadIdx.x;
    int wave = gtid >> 6;
    int lane = gtid & 63;
    int nw   = (gridDim.x * blockDim.x) >> 6;
    for (int e = wave; e < E; e += nw) {
        int s = src[e], d = dst[e];
        const float* xs = X + (size_t)s * D;
        float* ag = agg + (size_t)d * D;
        for (int c = lane; c < D; c += 64)
            atomicAdd(&ag[c], xs[c]);
    }
}

// ---------------------------------------------------------------- GEMM: C[R,256] (=|+=) (A[R,K]*inv)@W[K,256] (+bias)
__global__ __launch_bounds__(256)
void gemm_kernel(const float* __restrict__ A, const float* __restrict__ W,
                 float* __restrict__ C, const float* __restrict__ inv,
                 const float* __restrict__ bias, int R, int K, int accflag)
{
    __shared__ __align__(16) float As[16][68];
    __shared__ __align__(16) float Bs[16][68];
    const int bm = blockIdx.x << 6;
    const int bn = blockIdx.y << 6;
    const int tid = threadIdx.x;
    const int tr = tid >> 4, tc = tid & 15;
    float acc[4][4] = {{0.f}};

    for (int k0 = 0; k0 < K; k0 += 16) {
#pragma unroll
        for (int p = 0; p < 4; ++p) {
            int idx = (p << 8) + tid;
            int ar = idx >> 4, ac = idx & 15;
            int grow = bm + ar;
            float v = 0.f;
            if (grow < R) {
                v = A[(size_t)grow * K + (k0 + ac)];
                if (inv) v *= inv[grow];
            }
            As[ac][ar] = v;
        }
#pragma unroll
        for (int p = 0; p < 4; ++p) {
            int idx = (p << 8) + tid;
            int brr = idx >> 6, bc = idx & 63;
            Bs[brr][bc] = W[(size_t)(k0 + brr) * 256 + (bn + bc)];
        }
        __syncthreads();
#pragma unroll
        for (int kk = 0; kk < 16; ++kk) {
            const float4 av = *(const float4*)&As[kk][tr << 2];
            const float4 bv = *(const float4*)&Bs[kk][tc << 2];
            const float a[4] = {av.x, av.y, av.z, av.w};
            const float b[4] = {bv.x, bv.y, bv.z, bv.w};
#pragma unroll
            for (int ii = 0; ii < 4; ++ii)
#pragma unroll
                for (int jj = 0; jj < 4; ++jj)
                    acc[ii][jj] += a[ii] * b[jj];
        }
        __syncthreads();
    }

#pragma unroll
    for (int ii = 0; ii < 4; ++ii) {
        int grow = bm + (tr << 2) + ii;
        if (grow >= R) continue;
        float* cp = &C[(size_t)grow * 256 + bn + (tc << 2)];
        float4 r;
        r.x = acc[ii][0]; r.y = acc[ii][1]; r.z = acc[ii][2]; r.w = acc[ii][3];
        if (accflag) {
            const float4 old = *(const float4*)cp;
            r.x += old.x; r.y += old.y; r.z += old.z; r.w += old.w;
        } else if (bias) {
            const float4 bb = *(const float4*)&bias[bn + (tc << 2)];
            r.x += bb.x; r.y += bb.y; r.z += bb.z; r.w += bb.w;
        }
        *(float4*)cp = r;
    }
}

// ---------------------------------------------------------------- BatchNorm (train-mode, biased var) + ReLU
__global__ __launch_bounds__(256)
void bn_stats_kernel(const float* __restrict__ H, int R, float* __restrict__ stats)
{
    int c = threadIdx.x;              // 256 columns, one per thread
    int r0 = blockIdx.x * 128;
    int r1 = min(r0 + 128, R);
    float s = 0.f, ss = 0.f;
    for (int r = r0; r < r1; ++r) {
        float v = H[(size_t)r * 256 + c];
        s += v; ss += v * v;
    }
    atomicAdd(&stats[c], s);
    atomicAdd(&stats[256 + c], ss);
}

__global__ void bn_apply_kernel(float* __restrict__ H, int R, const float* __restrict__ stats,
                                const float* __restrict__ g, const float* __restrict__ beta)
{
    float invR = 1.0f / (float)R;
    size_t total = (size_t)R * 256;
    for (size_t i = blockIdx.x * (size_t)blockDim.x + threadIdx.x; i < total;
         i += (size_t)gridDim.x * blockDim.x) {
        int c = (int)(i & 255);
        float mu  = stats[c] * invR;
        float var = stats[256 + c] * invR - mu * mu;
        float sc  = rsqrtf(var + EPS_BN) * g[c];
        float v   = (H[i] - mu) * sc + beta[c];
        H[i] = fmaxf(v, 0.f);
    }
}

// ---------------------------------------------------------------- host
extern "C" void kernel_launch(void* const* d_in, const int* in_sizes, int n_in,
                              void* d_out, int out_size, void* d_ws, size_t ws_size,
                              hipStream_t stream)
{
    static const int Nn[4]   = {20000, 50000, 10000, 3000};   // drug, protein, side_effect, pathway
    static const int roff[4] = {0, 20000, 70000, 80000};      // row offsets in concat layout
    static const int rst[7]  = {0, 0, 1, 1, 2, 1, 3};         // src type per relation
    static const int rdt[7]  = {2, 1, 3, 2, 0, 0, 1};         // dst type per relation
    static const int coff[7] = {0, 10000, 60000, 63000, 73000, 93000, 113000}; // cnt offsets
    const int CNT_TOTAL = 163000;

    const float* x[4];
    for (int t = 0; t < 4; ++t) x[t] = (const float*)d_in[t];
    const int* src[7]; const int* dst[7]; int E[7];
    for (int i = 0; i < 7; ++i) {
        src[i] = (const int*)d_in[4 + 2 * i];
        dst[i] = (const int*)d_in[5 + 2 * i];
        E[i]   = in_sizes[4 + 2 * i];
    }
    const float* W1l = (const float*)d_in[18];
    const float* W1r = (const float*)d_in[19];
    const float* b1  = (const float*)d_in[20];
    const float* W2l = (const float*)d_in[21];
    const float* W2r = (const float*)d_in[22];
    const float* b2  = (const float*)d_in[23];
    const float* g1  = (const float*)d_in[24];
    const float* be1 = (const float*)d_in[25];
    const float* g2  = (const float*)d_in[26];
    const float* be2 = (const float*)d_in[27];
    float* out = (float*)d_out;
    (void)n_in; (void)out_size; (void)ws_size;

    // ---- workspace carve (≈138 MB total)
    char* w = (char*)d_ws;
    size_t off = 0;
    auto carve = [&](size_t bytes) -> float* {
        float* p = (float*)(w + off);
        off = (off + bytes + 255) & ~(size_t)255;
        return p;
    };
    float* cnt   = carve((size_t)CNT_TOTAL * 4);
    float* stats = carve((size_t)4 * 512 * 4);
    float* wsum  = carve((size_t)4 * 256 * 256 * 4);
    float* bsum  = carve((size_t)4 * 256 * 4);
    float* agg   = carve((size_t)50000 * 256 * 4);
    float* h     = carve((size_t)83000 * 256 * 4);

    // ---- per-dst counts (shared by both layers)
    hipMemsetAsync(cnt, 0, (size_t)CNT_TOTAL * 4, stream);
    for (int i = 0; i < 7; ++i)
        count_kernel<<<1024, 256, 0, stream>>>(dst[i], E[i], cnt + coff[i]);
    invert_kernel<<<(CNT_TOTAL + 255) / 256, 256, 0, stream>>>(cnt, CNT_TOTAL);

    for (int layer = 0; layer < 2; ++layer) {
        const int K = layer ? 256 : 128;
        const float* Wl = layer ? W2l : W1l;
        const float* Wr = layer ? W2r : W1r;
        const float* bb = layer ? b2  : b1;
        const float* gg = layer ? g2  : g1;
        const float* be = layer ? be2 : be1;
        float* dstbuf = layer ? out : h;

        // combined root weights
        wsum_kernel<<<(4 * K * 256 + 255) / 256, 256, 0, stream>>>(Wr, bb, wsum, bsum, K);

        // root transform: dstbuf[t] = x/h[t] @ Wr_sum[t] + b_sum[t]
        for (int t = 0; t < 4; ++t) {
            const float* At = layer ? (h + (size_t)roff[t] * 256) : x[t];
            gemm_kernel<<<dim3((Nn[t] + 63) / 64, 4), 256, 0, stream>>>(
                At, wsum + (size_t)t * K * 256, dstbuf + (size_t)roff[t] * 256,
                nullptr, bsum + t * 256, Nn[t], K, 0);
        }

        // per-relation: scatter-mean then project-accumulate
        for (int i = 0; i < 7; ++i) {
            int Nd = Nn[rdt[i]];
            hipMemsetAsync(agg, 0, (size_t)Nd * K * 4, stream);
            const float* Xs = layer ? (h + (size_t)roff[rst[i]] * 256) : x[rst[i]];
            scatter_kernel<<<2048, 256, 0, stream>>>(src[i], dst[i], E[i], Xs, agg, K);
            gemm_kernel<<<dim3((Nd + 63) / 64, 4), 256, 0, stream>>>(
                agg, Wl + (size_t)i * K * 256, dstbuf + (size_t)roff[rdt[i]] * 256,
                cnt + coff[i], nullptr, Nd, K, 1);
        }

        // BN + ReLU per node type
        hipMemsetAsync(stats, 0, (size_t)4 * 512 * 4, stream);
        for (int t = 0; t < 4; ++t)
            bn_stats_kernel<<<(Nn[t] + 127) / 128, 256, 0, stream>>>(
                dstbuf + (size_t)roff[t] * 256, Nn[t], stats + t * 512);
        for (int t = 0; t < 4; ++t)
            bn_apply_kernel<<<512, 256, 0, stream>>>(
                dstbuf + (size_t)roff[t] * 256, Nn[t], stats + t * 512, gg, be);
    }
}

// Round 2
// 2326.544 us; speedup vs baseline: 2.0686x; 2.0686x over previous
//
#include <hip/hip_runtime.h>

#define EPS_BN 1e-5f

struct RelMeta { int coff[7]; int rpoff[7]; int nd[7]; };

// ---------------------------------------------------------------- int degree histogram
__global__ void icount_kernel(const int* __restrict__ dst, int E, int* __restrict__ icnt)
{
    for (int e = blockIdx.x * blockDim.x + threadIdx.x; e < E; e += gridDim.x * blockDim.x)
        atomicAdd(&icnt[dst[e]], 1);
}

__global__ void invert_kernel(const int* __restrict__ icnt, float* __restrict__ inv, int n)
{
    for (int i = blockIdx.x * blockDim.x + threadIdx.x; i < n; i += gridDim.x * blockDim.x)
        inv[i] = 1.0f / (float)max(icnt[i], 1);
}

// ---------------------------------------------------------------- per-relation exclusive scan (1 block/relation)
__global__ __launch_bounds__(1024)
void scan_kernel(const int* __restrict__ icnt, int* __restrict__ rowptr, RelMeta m)
{
    int rel = blockIdx.x;
    const int* c = icnt + m.coff[rel];
    int* rp = rowptr + m.rpoff[rel];
    int n = m.nd[rel];
    __shared__ int lds[1024];
    int tid = threadIdx.x;
    int running = 0;
    if (tid == 0) rp[0] = 0;
    for (int s = 0; s < n; s += 1024) {
        int v = (s + tid < n) ? c[s + tid] : 0;
        lds[tid] = v;
        __syncthreads();
        for (int d = 1; d < 1024; d <<= 1) {
            int t = (tid >= d) ? lds[tid - d] : 0;
            __syncthreads();
            lds[tid] += t;
            __syncthreads();
        }
        if (s + tid < n) rp[s + tid + 1] = running + lds[tid];
        running += lds[1023];
        __syncthreads();
    }
}

// ---------------------------------------------------------------- CSR fill: bucket src ids by dst
__global__ void fill_kernel(const int* __restrict__ src, const int* __restrict__ dst, int E,
                            const int* __restrict__ rp, int* __restrict__ cur,
                            int* __restrict__ csr)
{
    for (int e = blockIdx.x * blockDim.x + threadIdx.x; e < E; e += gridDim.x * blockDim.x) {
        int d = dst[e];
        int pos = atomicAdd(&cur[d], 1);
        csr[rp[d] + pos] = src[e];
    }
}

// ---------------------------------------------------------------- gather-mean: one wave per dst row, no atomics
template <int D>
__global__ __launch_bounds__(256)
void gather_kernel(const int* __restrict__ csr, const int* __restrict__ rp,
                   const float* __restrict__ X, const float* __restrict__ invc,
                   float* __restrict__ agg, int Nd)
{
    int wid = (blockIdx.x * blockDim.x + threadIdx.x) >> 6;
    if (wid >= Nd) return;
    int lane = threadIdx.x & 63;
    constexpr int C = D / 64;                    // 2 (D=128) or 4 (D=256) floats per lane
    const float* Xl = X + lane * C;
    int beg = rp[wid], end = rp[wid + 1];
    float acc0[C] = {}, acc1[C] = {};
    int e = beg;
    for (; e + 2 <= end; e += 2) {
        int s0 = csr[e], s1 = csr[e + 1];
        const float* p0 = Xl + (size_t)s0 * D;
        const float* p1 = Xl + (size_t)s1 * D;
        if constexpr (C == 4) {
            float4 v0 = *(const float4*)p0;
            float4 v1 = *(const float4*)p1;
            acc0[0] += v0.x; acc0[1] += v0.y; acc0[2] += v0.z; acc0[3] += v0.w;
            acc1[0] += v1.x; acc1[1] += v1.y; acc1[2] += v1.z; acc1[3] += v1.w;
        } else {
            float2 v0 = *(const float2*)p0;
            float2 v1 = *(const float2*)p1;
            acc0[0] += v0.x; acc0[1] += v0.y;
            acc1[0] += v1.x; acc1[1] += v1.y;
        }
    }
    if (e < end) {
        int s0 = csr[e];
        const float* p0 = Xl + (size_t)s0 * D;
        if constexpr (C == 4) {
            float4 v0 = *(const float4*)p0;
            acc0[0] += v0.x; acc0[1] += v0.y; acc0[2] += v0.z; acc0[3] += v0.w;
        } else {
            float2 v0 = *(const float2*)p0;
            acc0[0] += v0.x; acc0[1] += v0.y;
        }
    }
    float inv = invc[wid];
    float* op = agg + (size_t)wid * D + lane * C;
    if constexpr (C == 4) {
        float4 o;
        o.x = (acc0[0] + acc1[0]) * inv;
        o.y = (acc0[1] + acc1[1]) * inv;
        o.z = (acc0[2] + acc1[2]) * inv;
        o.w = (acc0[3] + acc1[3]) * inv;
        *(float4*)op = o;
    } else {
        float2 o;
        o.x = (acc0[0] + acc1[0]) * inv;
        o.y = (acc0[1] + acc1[1]) * inv;
        *(float2*)op = o;
    }
}

// ---------------------------------------------------------------- combined root weights per dst type
// types: 0 drug {rels 4,5}, 1 protein {1,6}, 2 side_effect {0,3}, 3 pathway {2}
__global__ void wsum_kernel(const float* __restrict__ Wr, const float* __restrict__ br,
                            float* __restrict__ wsum, float* __restrict__ bsum, int K)
{
    const int nrel[4]  = {2, 2, 2, 1};
    const int rl[4][2] = {{4,5},{1,6},{0,3},{2,2}};
    int per = K * 256;
    for (int idx = blockIdx.x * blockDim.x + threadIdx.x; idx < 4 * per;
         idx += gridDim.x * blockDim.x) {
        int t = idx / per, o = idx - t * per;
        float s = Wr[rl[t][0] * per + o];
        if (nrel[t] > 1) s += Wr[rl[t][1] * per + o];
        wsum[idx] = s;
        if (idx < 4 * 256) {
            int tt = idx >> 8, oo = idx & 255;
            float sb = br[rl[tt][0] * 256 + oo];
            if (nrel[tt] > 1) sb += br[rl[tt][1] * 256 + oo];
            bsum[idx] = sb;
        }
    }
}

// ---------------------------------------------------------------- GEMM: C[R,256] (=|+=) A[R,K]@W[K,256] (+bias)
__global__ __launch_bounds__(256)
void gemm_kernel(const float* __restrict__ A, const float* __restrict__ W,
                 float* __restrict__ C, const float* __restrict__ bias, int R, int K, int accflag)
{
    __shared__ __align__(16) float As[16][68];
    __shared__ __align__(16) float Bs[16][68];
    const int bm = blockIdx.x << 6;
    const int bn = blockIdx.y << 6;
    const int tid = threadIdx.x;
    const int tr = tid >> 4, tc = tid & 15;
    float acc[4][4] = {{0.f}};

    for (int k0 = 0; k0 < K; k0 += 16) {
#pragma unroll
        for (int p = 0; p < 4; ++p) {
            int idx = (p << 8) + tid;
            int ar = idx >> 4, ac = idx & 15;
            int grow = bm + ar;
            float v = 0.f;
            if (grow < R) v = A[(size_t)grow * K + (k0 + ac)];
            As[ac][ar] = v;
        }
#pragma unroll
        for (int p = 0; p < 4; ++p) {
            int idx = (p << 8) + tid;
            int brr = idx >> 6, bc = idx & 63;
            Bs[brr][bc] = W[(size_t)(k0 + brr) * 256 + (bn + bc)];
        }
        __syncthreads();
#pragma unroll
        for (int kk = 0; kk < 16; ++kk) {
            const float4 av = *(const float4*)&As[kk][tr << 2];
            const float4 bv = *(const float4*)&Bs[kk][tc << 2];
            const float a[4] = {av.x, av.y, av.z, av.w};
            const float b[4] = {bv.x, bv.y, bv.z, bv.w};
#pragma unroll
            for (int ii = 0; ii < 4; ++ii)
#pragma unroll
                for (int jj = 0; jj < 4; ++jj)
                    acc[ii][jj] += a[ii] * b[jj];
        }
        __syncthreads();
    }

#pragma unroll
    for (int ii = 0; ii < 4; ++ii) {
        int grow = bm + (tr << 2) + ii;
        if (grow >= R) continue;
        float* cp = &C[(size_t)grow * 256 + bn + (tc << 2)];
        float4 r;
        r.x = acc[ii][0]; r.y = acc[ii][1]; r.z = acc[ii][2]; r.w = acc[ii][3];
        if (accflag) {
            const float4 old = *(const float4*)cp;
            r.x += old.x; r.y += old.y; r.z += old.z; r.w += old.w;
        } else if (bias) {
            const float4 bb = *(const float4*)&bias[bn + (tc << 2)];
            r.x += bb.x; r.y += bb.y; r.z += bb.z; r.w += bb.w;
        }
        *(float4*)cp = r;
    }
}

// ---------------------------------------------------------------- BatchNorm (train-mode, biased var) + ReLU
__global__ __launch_bounds__(256)
void bn_stats_kernel(const float* __restrict__ H, int R, float* __restrict__ stats)
{
    int c = threadIdx.x;
    int r0 = blockIdx.x * 128;
    int r1 = min(r0 + 128, R);
    float s = 0.f, ss = 0.f;
    for (int r = r0; r < r1; ++r) {
        float v = H[(size_t)r * 256 + c];
        s += v; ss += v * v;
    }
    atomicAdd(&stats[c], s);
    atomicAdd(&stats[256 + c], ss);
}

__global__ void bn_apply_kernel(float* __restrict__ H, int R, const float* __restrict__ stats,
                                const float* __restrict__ g, const float* __restrict__ beta)
{
    float invR = 1.0f / (float)R;
    size_t total = (size_t)R * 256;
    for (size_t i = blockIdx.x * (size_t)blockDim.x + threadIdx.x; i < total;
         i += (size_t)gridDim.x * blockDim.x) {
        int c = (int)(i & 255);
        float mu  = stats[c] * invR;
        float var = stats[256 + c] * invR - mu * mu;
        float sc  = rsqrtf(var + EPS_BN) * g[c];
        float v   = (H[i] - mu) * sc + beta[c];
        H[i] = fmaxf(v, 0.f);
    }
}

// ---------------------------------------------------------------- host
extern "C" void kernel_launch(void* const* d_in, const int* in_sizes, int n_in,
                              void* d_out, int out_size, void* d_ws, size_t ws_size,
                              hipStream_t stream)
{
    static const int Nn[4]   = {20000, 50000, 10000, 3000};   // drug, protein, side_effect, pathway
    static const int roff[4] = {0, 20000, 70000, 80000};      // row offsets in concat layout
    static const int rst[7]  = {0, 0, 1, 1, 2, 1, 3};         // src type per relation
    static const int rdt[7]  = {2, 1, 3, 2, 0, 0, 1};         // dst type per relation
    static const int coff[7] = {0, 10000, 60000, 63000, 73000, 93000, 113000}; // per-rel dst offsets
    static const int eoff[7] = {0, 500000, 900000, 1050000, 1450000, 1950000, 2350000};
    const int CNT_TOTAL = 163000;
    const int E_TOTAL   = 2500000;

    const float* x[4];
    for (int t = 0; t < 4; ++t) x[t] = (const float*)d_in[t];
    const int* src[7]; const int* dst[7]; int E[7];
    for (int i = 0; i < 7; ++i) {
        src[i] = (const int*)d_in[4 + 2 * i];
        dst[i] = (const int*)d_in[5 + 2 * i];
        E[i]   = in_sizes[4 + 2 * i];
    }
    const float* W1l = (const float*)d_in[18];
    const float* W1r = (const float*)d_in[19];
    const float* b1  = (const float*)d_in[20];
    const float* W2l = (const float*)d_in[21];
    const float* W2r = (const float*)d_in[22];
    const float* b2  = (const float*)d_in[23];
    const float* g1  = (const float*)d_in[24];
    const float* be1 = (const float*)d_in[25];
    const float* g2  = (const float*)d_in[26];
    const float* be2 = (const float*)d_in[27];
    float* out = (float*)d_out;
    (void)n_in; (void)out_size; (void)ws_size;

    // ---- workspace carve
    char* w = (char*)d_ws;
    size_t off = 0;
    auto carve = [&](size_t bytes) -> void* {
        void* p = (void*)(w + off);
        off = (off + bytes + 255) & ~(size_t)255;
        return p;
    };
    int*   icnt   = (int*)carve((size_t)CNT_TOTAL * 4);
    int*   cur    = (int*)carve((size_t)CNT_TOTAL * 4);
    int*   rowptr = (int*)carve((size_t)(CNT_TOTAL + 7) * 4);
    int*   csr    = (int*)carve((size_t)E_TOTAL * 4);
    float* cnt    = (float*)carve((size_t)CNT_TOTAL * 4);
    float* stats  = (float*)carve((size_t)4 * 512 * 4);
    float* wsum   = (float*)carve((size_t)4 * 256 * 256 * 4);
    float* bsum   = (float*)carve((size_t)4 * 256 * 4);
    float* agg    = (float*)carve((size_t)50000 * 256 * 4);
    float* h      = (float*)carve((size_t)83000 * 256 * 4);

    RelMeta meta;
    for (int i = 0; i < 7; ++i) {
        meta.coff[i]  = coff[i];
        meta.rpoff[i] = coff[i] + i;   // each relation gets Nd+1 rowptr slots
        meta.nd[i]    = Nn[rdt[i]];
    }

    // ---- CSR build (shared by both layers)
    hipMemsetAsync(icnt, 0, (size_t)CNT_TOTAL * 4, stream);
    hipMemsetAsync(cur,  0, (size_t)CNT_TOTAL * 4, stream);
    for (int i = 0; i < 7; ++i)
        icount_kernel<<<512, 256, 0, stream>>>(dst[i], E[i], icnt + coff[i]);
    scan_kernel<<<7, 1024, 0, stream>>>(icnt, rowptr, meta);
    invert_kernel<<<(CNT_TOTAL + 255) / 256, 256, 0, stream>>>(icnt, cnt, CNT_TOTAL);
    for (int i = 0; i < 7; ++i)
        fill_kernel<<<1024, 256, 0, stream>>>(src[i], dst[i], E[i],
                                              rowptr + meta.rpoff[i], cur + coff[i],
                                              csr + eoff[i]);

    for (int layer = 0; layer < 2; ++layer) {
        const int K = layer ? 256 : 128;
        const float* Wl = layer ? W2l : W1l;
        const float* Wr = layer ? W2r : W1r;
        const float* bb = layer ? b2  : b1;
        const float* gg = layer ? g2  : g1;
        const float* be = layer ? be2 : be1;
        float* dstbuf = layer ? out : h;

        wsum_kernel<<<(4 * K * 256 + 255) / 256, 256, 0, stream>>>(Wr, bb, wsum, bsum, K);

        // root transform: dstbuf[t] = x/h[t] @ Wr_sum[t] + b_sum[t]
        for (int t = 0; t < 4; ++t) {
            const float* At = layer ? (h + (size_t)roff[t] * 256) : x[t];
            gemm_kernel<<<dim3((Nn[t] + 63) / 64, 4), 256, 0, stream>>>(
                At, wsum + (size_t)t * K * 256, dstbuf + (size_t)roff[t] * 256,
                bsum + t * 256, Nn[t], K, 0);
        }

        // per-relation: gather-mean then project-accumulate
        for (int i = 0; i < 7; ++i) {
            int Nd = Nn[rdt[i]];
            const float* Xs = layer ? (h + (size_t)roff[rst[i]] * 256) : x[rst[i]];
            if (K == 128)
                gather_kernel<128><<<(Nd + 3) / 4, 256, 0, stream>>>(
                    csr + eoff[i], rowptr + meta.rpoff[i], Xs, cnt + coff[i], agg, Nd);
            else
                gather_kernel<256><<<(Nd + 3) / 4, 256, 0, stream>>>(
                    csr + eoff[i], rowptr + meta.rpoff[i], Xs, cnt + coff[i], agg, Nd);
            gemm_kernel<<<dim3((Nd + 63) / 64, 4), 256, 0, stream>>>(
                agg, Wl + (size_t)i * K * 256, dstbuf + (size_t)roff[rdt[i]] * 256,
                nullptr, Nd, K, 1);
        }

        // BN + ReLU per node type
        hipMemsetAsync(stats, 0, (size_t)4 * 512 * 4, stream);
        for (int t = 0; t < 4; ++t)
            bn_stats_kernel<<<(Nn[t] + 127) / 128, 256, 0, stream>>>(
                dstbuf + (size_t)roff[t] * 256, Nn[t], stats + t * 512);
        for (int t = 0; t < 4; ++t)
            bn_apply_kernel<<<512, 256, 0, stream>>>(
                dstbuf + (size_t)roff[t] * 256, Nn[t], stats + t * 512, gg, be);
    }
}

// Round 3
// 1502.990 us; speedup vs baseline: 3.2021x; 1.5479x over previous
//
#include <hip/hip_runtime.h>

#define EPS_BN 1e-5f

typedef short bf16x8 __attribute__((ext_vector_type(8)));
typedef float f32x4 __attribute__((ext_vector_type(4)));

struct RelMeta { int coff[7]; int rpoff[7]; int nd[7]; };

__device__ __forceinline__ unsigned short f2b(float f)
{
    union { float f; unsigned int u; } c; c.f = f;
    unsigned int u = c.u + 0x7FFFu + ((c.u >> 16) & 1u);
    return (unsigned short)(u >> 16);
}
__device__ __forceinline__ float blo(unsigned int u)
{
    union { unsigned int u; float f; } c; c.u = u << 16; return c.f;
}
__device__ __forceinline__ float bhi(unsigned int u)
{
    union { unsigned int u; float f; } c; c.u = u & 0xFFFF0000u; return c.f;
}

// ---------------------------------------------------------------- CSR build
__global__ void icount_kernel(const int* __restrict__ dst, int E, int* __restrict__ icnt)
{
    for (int e = blockIdx.x * blockDim.x + threadIdx.x; e < E; e += gridDim.x * blockDim.x)
        atomicAdd(&icnt[dst[e]], 1);
}

__global__ void invert_kernel(const int* __restrict__ icnt, float* __restrict__ inv, int n)
{
    for (int i = blockIdx.x * blockDim.x + threadIdx.x; i < n; i += gridDim.x * blockDim.x)
        inv[i] = 1.0f / (float)max(icnt[i], 1);
}

__global__ __launch_bounds__(1024)
void scan_kernel(const int* __restrict__ icnt, int* __restrict__ rowptr, RelMeta m)
{
    int rel = blockIdx.x;
    const int* c = icnt + m.coff[rel];
    int* rp = rowptr + m.rpoff[rel];
    int n = m.nd[rel];
    __shared__ int lds[1024];
    int tid = threadIdx.x;
    int running = 0;
    if (tid == 0) rp[0] = 0;
    for (int s = 0; s < n; s += 1024) {
        int v = (s + tid < n) ? c[s + tid] : 0;
        lds[tid] = v;
        __syncthreads();
        for (int d = 1; d < 1024; d <<= 1) {
            int t = (tid >= d) ? lds[tid - d] : 0;
            __syncthreads();
            lds[tid] += t;
            __syncthreads();
        }
        if (s + tid < n) rp[s + tid + 1] = running + lds[tid];
        running += lds[1023];
        __syncthreads();
    }
}

__global__ void fill_kernel(const int* __restrict__ src, const int* __restrict__ dst, int E,
                            const int* __restrict__ rp, int* __restrict__ cur,
                            int* __restrict__ csr)
{
    for (int e = blockIdx.x * blockDim.x + threadIdx.x; e < E; e += gridDim.x * blockDim.x) {
        int d = dst[e];
        int pos = atomicAdd(&cur[d], 1);
        csr[rp[d] + pos] = src[e];
    }
}

// ---------------------------------------------------------------- f32 -> bf16 bulk convert
__global__ void tob16_kernel(const float* __restrict__ in, unsigned short* __restrict__ out, int n4)
{
    for (int i = blockIdx.x * blockDim.x + threadIdx.x; i < n4; i += gridDim.x * blockDim.x) {
        float4 v = ((const float4*)in)[i];
        uint2 o;
        o.x = (unsigned int)f2b(v.x) | ((unsigned int)f2b(v.y) << 16);
        o.y = (unsigned int)f2b(v.z) | ((unsigned int)f2b(v.w) << 16);
        ((uint2*)out)[i] = o;
    }
}

// ---------------------------------------------------------------- gather-mean (bf16 in/out, f32 accum)
template <int D>
__global__ __launch_bounds__(256)
void gather_kernel(const int* __restrict__ csr, const int* __restrict__ rp,
                   const unsigned short* __restrict__ X, const float* __restrict__ invc,
                   unsigned short* __restrict__ agg, int Nd)
{
    int wid = (blockIdx.x * blockDim.x + threadIdx.x) >> 6;
    if (wid >= Nd) return;
    int lane = threadIdx.x & 63;
    constexpr int C  = D / 64;      // bf16 per lane: 2 (D=128) or 4 (D=256)
    constexpr int CU = C / 2;       // uints per lane
    const int rowu = D / 2;         // uints per row
    const unsigned int* X32 = (const unsigned int*)X;
    int lo = lane * CU;
    int beg = rp[wid], end = rp[wid + 1];
    float acc0[C] = {}, acc1[C] = {};
    int e = beg;
    for (; e + 2 <= end; e += 2) {
        int s0 = csr[e], s1 = csr[e + 1];
        const unsigned int* p0 = X32 + (size_t)s0 * rowu + lo;
        const unsigned int* p1 = X32 + (size_t)s1 * rowu + lo;
        if constexpr (CU == 2) {
            uint2 v0 = *(const uint2*)p0;
            uint2 v1 = *(const uint2*)p1;
            acc0[0] += blo(v0.x); acc0[1] += bhi(v0.x); acc0[2] += blo(v0.y); acc0[3] += bhi(v0.y);
            acc1[0] += blo(v1.x); acc1[1] += bhi(v1.x); acc1[2] += blo(v1.y); acc1[3] += bhi(v1.y);
        } else {
            unsigned int v0 = *p0, v1 = *p1;
            acc0[0] += blo(v0); acc0[1] += bhi(v0);
            acc1[0] += blo(v1); acc1[1] += bhi(v1);
        }
    }
    if (e < end) {
        int s0 = csr[e];
        const unsigned int* p0 = X32 + (size_t)s0 * rowu + lo;
        if constexpr (CU == 2) {
            uint2 v0 = *(const uint2*)p0;
            acc0[0] += blo(v0.x); acc0[1] += bhi(v0.x); acc0[2] += blo(v0.y); acc0[3] += bhi(v0.y);
        } else {
            unsigned int v0 = *p0;
            acc0[0] += blo(v0); acc0[1] += bhi(v0);
        }
    }
    float inv = invc[wid];
    unsigned int* op = (unsigned int*)agg + (size_t)wid * rowu + lo;
    if constexpr (CU == 2) {
        uint2 o;
        o.x = (unsigned int)f2b((acc0[0] + acc1[0]) * inv) | ((unsigned int)f2b((acc0[1] + acc1[1]) * inv) << 16);
        o.y = (unsigned int)f2b((acc0[2] + acc1[2]) * inv) | ((unsigned int)f2b((acc0[3] + acc1[3]) * inv) << 16);
        *(uint2*)op = o;
    } else {
        *op = (unsigned int)f2b((acc0[0] + acc1[0]) * inv) | ((unsigned int)f2b((acc0[1] + acc1[1]) * inv) << 16);
    }
}

// ---------------------------------------------------------------- weight prep: sum roots, transpose to [N][K] bf16
__global__ void wtrans_kernel(const float* __restrict__ Wr, const float* __restrict__ Wl,
                              const float* __restrict__ br,
                              unsigned short* __restrict__ wsumT, unsigned short* __restrict__ WlT,
                              float* __restrict__ bsum, int K)
{
    const int nrel[4]  = {2, 2, 2, 1};
    const int rl[4][2] = {{4,5},{1,6},{0,3},{2,2}};
    int per = 256 * K;
    int tot = 11 * per;
    if (blockIdx.x == 0 && threadIdx.x < 1024) {
        int t = threadIdx.x >> 8, n = threadIdx.x & 255;
        float s = br[rl[t][0] * 256 + n];
        if (nrel[t] > 1) s += br[rl[t][1] * 256 + n];
        bsum[t * 256 + n] = s;
    }
    for (int idx = blockIdx.x * blockDim.x + threadIdx.x; idx < tot;
         idx += gridDim.x * blockDim.x) {
        if (idx < 4 * per) {
            int t = idx / per, rem = idx - t * per;
            int n = rem / K, k = rem - n * K;
            float s = Wr[(size_t)rl[t][0] * per + k * 256 + n];
            if (nrel[t] > 1) s += Wr[(size_t)rl[t][1] * per + k * 256 + n];
            wsumT[idx] = f2b(s);
        } else {
            int j = idx - 4 * per;
            int r = j / per, rem = j - r * per;
            int n = rem / K, k = rem - n * K;
            WlT[j] = f2b(Wl[(size_t)r * per + k * 256 + n]);
        }
    }
}

// ---------------------------------------------------------------- fused MFMA GEMM
// C[R,256] = concat_s(A_s[R,K]) @ concat_s(B_s[256,K]^T) + bias, bf16 in, f32 acc
struct GemmCfg {
    const unsigned short* A0; const unsigned short* A1; const unsigned short* A2;
    const unsigned short* B0; const unsigned short* B1; const unsigned short* B2;
    const float* bias;
    float* outF; unsigned short* outB;
    int R, K, kshift, nsrc, outf32;
};

__global__ __launch_bounds__(256)
void gemm_mfma(GemmCfg g)
{
    __shared__ __align__(16) unsigned short Atile[2][128 * 32];
    __shared__ __align__(16) unsigned short Btile[2][128 * 32];

    const int tid = threadIdx.x;
    const int bm = blockIdx.x << 7;
    const int bn = blockIdx.y << 7;
    const int w = tid >> 6, l = tid & 63;
    const int wr = w >> 1, wc = w & 1;

    const unsigned short* Asrc[3] = {g.A0, g.A1, g.A2};
    const unsigned short* Bsrc[3] = {g.B0, g.B1, g.B2};
    const int steps = (g.nsrc * g.K) >> 5;
    const int kmask = g.K - 1;

    // staging: 512 16B-chunks (A) + 512 (B), 2 each per thread
    const int ar0 = tid >> 2,          ac0 = tid & 3;
    const int ar1 = (tid + 256) >> 2,  ac1 = (tid + 256) & 3;
    const int wA0 = ar0 * 32 + ((ac0 ^ ((ar0 >> 1) & 3)) << 3);   // ushort idx
    const int wA1 = ar1 * 32 + ((ac1 ^ ((ar1 >> 1) & 3)) << 3);

    uint4 rA0, rA1, rB0, rB1;
    auto stage_load = [&](int st) {
        int kglob = st << 5;
        int s  = kglob >> g.kshift;
        int kk = kglob & kmask;
        const unsigned short* As = Asrc[s];
        const unsigned short* Bs = Bsrc[s];
        uint4 z; z.x = z.y = z.z = z.w = 0u;
        int r0 = bm + ar0, r1 = bm + ar1;
        rA0 = (r0 < g.R) ? *(const uint4*)(As + (size_t)r0 * g.K + kk + ac0 * 8) : z;
        rA1 = (r1 < g.R) ? *(const uint4*)(As + (size_t)r1 * g.K + kk + ac1 * 8) : z;
        rB0 = *(const uint4*)(Bs + (size_t)(bn + ar0) * g.K + kk + ac0 * 8);
        rB1 = *(const uint4*)(Bs + (size_t)(bn + ar1) * g.K + kk + ac1 * 8);
    };
    auto stage_write = [&](int st) {
        unsigned short* At = Atile[st & 1];
        unsigned short* Bt = Btile[st & 1];
        *(uint4*)(At + wA0) = rA0;
        *(uint4*)(At + wA1) = rA1;
        *(uint4*)(Bt + wA0) = rB0;
        *(uint4*)(Bt + wA1) = rB1;
    };

    f32x4 acc[4][4];
#pragma unroll
    for (int i = 0; i < 4; ++i)
#pragma unroll
        for (int j = 0; j < 4; ++j)
            acc[i][j] = (f32x4){0.f, 0.f, 0.f, 0.f};

    // lane read bases (mf/nf offset = +1024 ushorts per 16 rows; swizzle invariant mod 16 rows)
    const int ra = wr * 64 + (l & 15);
    const int rb = wc * 64 + (l & 15);
    const int ck = l >> 4;
    const int aoff = ra * 32 + ((ck ^ ((ra >> 1) & 3)) << 3);
    const int boff = rb * 32 + ((ck ^ ((rb >> 1) & 3)) << 3);

    stage_load(0);
    stage_write(0);
    for (int st = 0; st < steps; ++st) {
        __syncthreads();
        if (st + 1 < steps) stage_load(st + 1);
        const unsigned short* At = Atile[st & 1];
        const unsigned short* Bt = Btile[st & 1];
        bf16x8 af[4], bfr[4];
#pragma unroll
        for (int i = 0; i < 4; ++i) {
            af[i]  = *(const bf16x8*)(At + aoff + i * 512);
            bfr[i] = *(const bf16x8*)(Bt + boff + i * 512);
        }
#pragma unroll
        for (int mi = 0; mi < 4; ++mi)
#pragma unroll
            for (int ni = 0; ni < 4; ++ni)
                acc[mi][ni] = __builtin_amdgcn_mfma_f32_16x16x32_bf16(
                    af[mi], bfr[ni], acc[mi][ni], 0, 0, 0);
        if (st + 1 < steps) stage_write(st + 1);
    }

    // epilogue: D row = (l>>4)*4 + j, col = l&15 within each 16x16 frag
    const int orow0 = bm + wr * 64 + ((l >> 4) << 2);
    const int ocol0 = bn + wc * 64 + (l & 15);
#pragma unroll
    for (int ni = 0; ni < 4; ++ni) {
        int col = ocol0 + ni * 16;
        float bv = g.bias[col];
#pragma unroll
        for (int mi = 0; mi < 4; ++mi) {
#pragma unroll
            for (int j = 0; j < 4; ++j) {
                int row = orow0 + mi * 16 + j;
                if (row < g.R) {
                    float v = acc[mi][ni][j] + bv;
                    if (g.outf32) g.outF[(size_t)row * 256 + col] = v;
                    else          g.outB[(size_t)row * 256 + col] = f2b(v);
                }
            }
        }
    }
}

// ---------------------------------------------------------------- BatchNorm (train-mode, biased var) + ReLU
__global__ __launch_bounds__(256)
void bn_stats_f32(const float* __restrict__ H, int R, float* __restrict__ stats)
{
    int c = threadIdx.x;
    int r0 = blockIdx.x * 128, r1 = min(r0 + 128, R);
    float s = 0.f, ss = 0.f;
    for (int r = r0; r < r1; ++r) {
        float v = H[(size_t)r * 256 + c];
        s += v; ss += v * v;
    }
    atomicAdd(&stats[c], s);
    atomicAdd(&stats[256 + c], ss);
}

__global__ __launch_bounds__(256)
void bn_stats_b16(const unsigned short* __restrict__ H, int R, float* __restrict__ stats)
{
    int c = threadIdx.x;
    int r0 = blockIdx.x * 128, r1 = min(r0 + 128, R);
    float s = 0.f, ss = 0.f;
    for (int r = r0; r < r1; ++r) {
        unsigned int u = H[(size_t)r * 256 + c];
        union { unsigned int u; float f; } cv; cv.u = u << 16;
        s += cv.f; ss += cv.f * cv.f;
    }
    atomicAdd(&stats[c], s);
    atomicAdd(&stats[256 + c], ss);
}

__global__ void bn_apply_f32(float* __restrict__ H, int R, const float* __restrict__ stats,
                             const float* __restrict__ g, const float* __restrict__ beta)
{
    float invR = 1.0f / (float)R;
    size_t total = (size_t)R * 256;
    for (size_t i = blockIdx.x * (size_t)blockDim.x + threadIdx.x; i < total;
         i += (size_t)gridDim.x * blockDim.x) {
        int c = (int)(i & 255);
        float mu  = stats[c] * invR;
        float var = stats[256 + c] * invR - mu * mu;
        float sc  = rsqrtf(var + EPS_BN) * g[c];
        float v   = (H[i] - mu) * sc + beta[c];
        H[i] = fmaxf(v, 0.f);
    }
}

__global__ void bn_apply_b16(unsigned short* __restrict__ H, int R, const float* __restrict__ stats,
                             const float* __restrict__ g, const float* __restrict__ beta)
{
    float invR = 1.0f / (float)R;
    size_t total = (size_t)R * 256;
    for (size_t i = blockIdx.x * (size_t)blockDim.x + threadIdx.x; i < total;
         i += (size_t)gridDim.x * blockDim.x) {
        int c = (int)(i & 255);
        float mu  = stats[c] * invR;
        float var = stats[256 + c] * invR - mu * mu;
        float sc  = rsqrtf(var + EPS_BN) * g[c];
        union { unsigned int u; float f; } cv; cv.u = (unsigned int)H[i] << 16;
        float v = (cv.f - mu) * sc + beta[c];
        H[i] = f2b(fmaxf(v, 0.f));
    }
}

// ---------------------------------------------------------------- host
extern "C" void kernel_launch(void* const* d_in, const int* in_sizes, int n_in,
                              void* d_out, int out_size, void* d_ws, size_t ws_size,
                              hipStream_t stream)
{
    static const int Nn[4]   = {20000, 50000, 10000, 3000};   // drug, protein, side_effect, pathway
    static const int roff[4] = {0, 20000, 70000, 80000};
    static const int rst[7]  = {0, 0, 1, 1, 2, 1, 3};
    static const int rdt[7]  = {2, 1, 3, 2, 0, 0, 1};
    static const int coff[7] = {0, 10000, 60000, 63000, 73000, 93000, 113000};
    static const int eoff[7] = {0, 500000, 900000, 1050000, 1450000, 1950000, 2350000};
    static const int trels[4][2] = {{4,5},{1,6},{0,3},{2,-1}};
    static const int tnrel[4]    = {2, 2, 2, 1};
    const int CNT_TOTAL = 163000;
    const int E_TOTAL   = 2500000;

    const float* x[4];
    for (int t = 0; t < 4; ++t) x[t] = (const float*)d_in[t];
    const int* src[7]; const int* dst[7]; int E[7];
    for (int i = 0; i < 7; ++i) {
        src[i] = (const int*)d_in[4 + 2 * i];
        dst[i] = (const int*)d_in[5 + 2 * i];
        E[i]   = in_sizes[4 + 2 * i];
    }
    const float* W1l = (const float*)d_in[18];
    const float* W1r = (const float*)d_in[19];
    const float* b1  = (const float*)d_in[20];
    const float* W2l = (const float*)d_in[21];
    const float* W2r = (const float*)d_in[22];
    const float* b2  = (const float*)d_in[23];
    const float* g1  = (const float*)d_in[24];
    const float* be1 = (const float*)d_in[25];
    const float* g2  = (const float*)d_in[26];
    const float* be2 = (const float*)d_in[27];
    float* out = (float*)d_out;
    (void)n_in; (void)out_size; (void)ws_size;

    // ---- workspace carve (~130 MB)
    char* w = (char*)d_ws;
    size_t off = 0;
    auto carve = [&](size_t bytes) -> void* {
        void* p = (void*)(w + off);
        off = (off + bytes + 255) & ~(size_t)255;
        return p;
    };
    int*   icnt   = (int*)carve((size_t)CNT_TOTAL * 4);
    int*   cur    = (int*)carve((size_t)CNT_TOTAL * 4);
    int*   rowptr = (int*)carve((size_t)(CNT_TOTAL + 7) * 4);
    int*   csr    = (int*)carve((size_t)E_TOTAL * 4);
    float* cnt    = (float*)carve((size_t)CNT_TOTAL * 4);
    float* stats  = (float*)carve((size_t)4 * 512 * 4);
    float* bsum   = (float*)carve((size_t)4 * 256 * 4);
    unsigned short* wsumT = (unsigned short*)carve((size_t)4 * 256 * 256 * 2);
    unsigned short* WlT   = (unsigned short*)carve((size_t)7 * 256 * 256 * 2);
    unsigned short* xb    = (unsigned short*)carve((size_t)83000 * 128 * 2);
    unsigned short* hb    = (unsigned short*)carve((size_t)83000 * 256 * 2);
    unsigned short* aggA  = (unsigned short*)carve((size_t)50000 * 256 * 2);
    unsigned short* aggB  = (unsigned short*)carve((size_t)50000 * 256 * 2);

    RelMeta meta;
    for (int i = 0; i < 7; ++i) {
        meta.coff[i]  = coff[i];
        meta.rpoff[i] = coff[i] + i;
        meta.nd[i]    = Nn[rdt[i]];
    }

    // ---- CSR build (shared by both layers)
    hipMemsetAsync(icnt, 0, (size_t)CNT_TOTAL * 4, stream);
    hipMemsetAsync(cur,  0, (size_t)CNT_TOTAL * 4, stream);
    for (int i = 0; i < 7; ++i)
        icount_kernel<<<512, 256, 0, stream>>>(dst[i], E[i], icnt + coff[i]);
    scan_kernel<<<7, 1024, 0, stream>>>(icnt, rowptr, meta);
    invert_kernel<<<(CNT_TOTAL + 255) / 256, 256, 0, stream>>>(icnt, cnt, CNT_TOTAL);
    for (int i = 0; i < 7; ++i)
        fill_kernel<<<1024, 256, 0, stream>>>(src[i], dst[i], E[i],
                                              rowptr + meta.rpoff[i], cur + coff[i],
                                              csr + eoff[i]);

    // ---- x -> bf16 once
    for (int t = 0; t < 4; ++t)
        tob16_kernel<<<1024, 256, 0, stream>>>(x[t], xb + (size_t)roff[t] * 128, Nn[t] * 128 / 4);

    for (int layer = 0; layer < 2; ++layer) {
        const int K = layer ? 256 : 128;
        const int kshift = layer ? 8 : 7;
        const float* Wl = layer ? W2l : W1l;
        const float* Wr = layer ? W2r : W1r;
        const float* bb = layer ? b2  : b1;
        const float* gg = layer ? g2  : g1;
        const float* be = layer ? be2 : be1;

        wtrans_kernel<<<1024, 256, 0, stream>>>(Wr, Wl, bb, wsumT, WlT, bsum, K);

        for (int t = 0; t < 4; ++t) {
            unsigned short* aggs[2] = {aggA, aggB};
            for (int j = 0; j < tnrel[t]; ++j) {
                int r = trels[t][j];
                const unsigned short* Xs = layer ? (hb + (size_t)roff[rst[r]] * 256)
                                                 : (xb + (size_t)roff[rst[r]] * 128);
                if (K == 128)
                    gather_kernel<128><<<(Nn[t] + 3) / 4, 256, 0, stream>>>(
                        csr + eoff[r], rowptr + meta.rpoff[r], Xs, cnt + coff[r], aggs[j], Nn[t]);
                else
                    gather_kernel<256><<<(Nn[t] + 3) / 4, 256, 0, stream>>>(
                        csr + eoff[r], rowptr + meta.rpoff[r], Xs, cnt + coff[r], aggs[j], Nn[t]);
            }
            GemmCfg cfg;
            cfg.A0 = layer ? (hb + (size_t)roff[t] * 256) : (xb + (size_t)roff[t] * 128);
            cfg.A1 = aggA;
            cfg.A2 = (tnrel[t] > 1) ? aggB : aggA;
            cfg.B0 = wsumT + (size_t)t * 256 * K;
            cfg.B1 = WlT + (size_t)trels[t][0] * 256 * K;
            cfg.B2 = (tnrel[t] > 1) ? (WlT + (size_t)trels[t][1] * 256 * K) : cfg.B1;
            cfg.bias = bsum + t * 256;
            cfg.outF = out + (size_t)roff[t] * 256;
            cfg.outB = hb + (size_t)roff[t] * 256;
            cfg.R = Nn[t]; cfg.K = K; cfg.kshift = kshift;
            cfg.nsrc = 1 + tnrel[t]; cfg.outf32 = layer;
            gemm_mfma<<<dim3((Nn[t] + 127) / 128, 2), 256, 0, stream>>>(cfg);
        }

        // BN + ReLU per node type
        hipMemsetAsync(stats, 0, (size_t)4 * 512 * 4, stream);
        if (layer == 0) {
            for (int t = 0; t < 4; ++t)
                bn_stats_b16<<<(Nn[t] + 127) / 128, 256, 0, stream>>>(
                    hb + (size_t)roff[t] * 256, Nn[t], stats + t * 512);
            for (int t = 0; t < 4; ++t)
                bn_apply_b16<<<512, 256, 0, stream>>>(
                    hb + (size_t)roff[t] * 256, Nn[t], stats + t * 512, gg, be);
        } else {
            for (int t = 0; t < 4; ++t)
                bn_stats_f32<<<(Nn[t] + 127) / 128, 256, 0, stream>>>(
                    out + (size_t)roff[t] * 256, Nn[t], stats + t * 512);
            for (int t = 0; t < 4; ++t)
                bn_apply_f32<<<512, 256, 0, stream>>>(
                    out + (size_t)roff[t] * 256, Nn[t], stats + t * 512, gg, be);
        }
    }
}

// Round 4
// 1189.159 us; speedup vs baseline: 4.0471x; 1.2639x over previous
//
#include <hip/hip_runtime.h>

#define EPS_BN 1e-5f

typedef short bf16x8 __attribute__((ext_vector_type(8)));
typedef float f32x4 __attribute__((ext_vector_type(4)));

__device__ __forceinline__ unsigned short f2b(float f)
{
    union { float f; unsigned int u; } c; c.f = f;
    unsigned int u = c.u + 0x7FFFu + ((c.u >> 16) & 1u);
    return (unsigned short)(u >> 16);
}
__device__ __forceinline__ float blo(unsigned int u)
{
    union { unsigned int u; float f; } c; c.u = u << 16; return c.f;
}
__device__ __forceinline__ float bhi(unsigned int u)
{
    union { unsigned int u; float f; } c; c.u = u & 0xFFFF0000u; return c.f;
}

// relation / type index helpers (branchless compare-sums)
__device__ __forceinline__ int relof_e(int e) {
    return (e>=500000)+(e>=900000)+(e>=1050000)+(e>=1450000)+(e>=1950000)+(e>=2350000);
}
__device__ __forceinline__ int relof_n(int i) {
    return (i>=10000)+(i>=60000)+(i>=63000)+(i>=73000)+(i>=93000)+(i>=113000);
}
__device__ __forceinline__ int eoff_of(int r) {
    return r<1?0 : r<2?500000 : r<3?900000 : r<4?1050000 : r<5?1450000 : r<6?1950000 : 2350000;
}
__device__ __forceinline__ int coff_of(int r) {
    return r<1?0 : r<2?10000 : r<3?60000 : r<4?63000 : r<5?73000 : r<6?93000 : 113000;
}
__device__ __forceinline__ int typ_of(int row) { return (row>=20000)+(row>=70000)+(row>=80000); }
__device__ __forceinline__ int nbound(int t)   { return t<1?20000 : t<2?70000 : t<3?80000 : 83000; }
__device__ __forceinline__ float invR_of(int t){ return t<1?5e-5f : t<2?2e-5f : t<3?1e-4f : (1.0f/3000.0f); }

struct Graph { const int* src[7]; const int* dst[7]; };

__device__ __forceinline__ void relptrs(const Graph& g, int r, const int*& sp, const int*& dp)
{
    sp = g.src[0]; dp = g.dst[0];
    if (r==1){sp=g.src[1];dp=g.dst[1];}
    if (r==2){sp=g.src[2];dp=g.dst[2];}
    if (r==3){sp=g.src[3];dp=g.dst[3];}
    if (r==4){sp=g.src[4];dp=g.dst[4];}
    if (r==5){sp=g.src[5];dp=g.dst[5];}
    if (r==6){sp=g.src[6];dp=g.dst[6];}
}

// ---------------------------------------------------------------- degree histogram (all rels, 1 launch)
__global__ void count_all(Graph g, int* __restrict__ icnt)
{
    for (int e = blockIdx.x * blockDim.x + threadIdx.x; e < 2500000; e += gridDim.x * blockDim.x) {
        int r = relof_e(e);
        const int *sp, *dp; relptrs(g, r, sp, dp);
        int le = e - eoff_of(r);
        atomicAdd(&icnt[coff_of(r) + dp[le]], 1);
    }
}

// ---------------------------------------------------------------- 3-phase global scan
__global__ __launch_bounds__(1024)
void scan1(const int* __restrict__ icnt, int* __restrict__ scanbuf, int* __restrict__ bsums)
{
    __shared__ int lds[1024];
    int tid = threadIdx.x;
    int gid = blockIdx.x * 1024 + tid;
    int v = (gid < 163000) ? icnt[gid] : 0;
    lds[tid] = v;
    __syncthreads();
    for (int d = 1; d < 1024; d <<= 1) {
        int t = (tid >= d) ? lds[tid - d] : 0;
        __syncthreads();
        lds[tid] += t;
        __syncthreads();
    }
    scanbuf[gid] = lds[tid];                  // inclusive within block
    if (tid == 1023) bsums[blockIdx.x] = lds[1023];
}

__global__ __launch_bounds__(256)
void scan2(int* __restrict__ bsums)          // exclusive scan of 160 partials, in place
{
    __shared__ int lds[256];
    int tid = threadIdx.x;
    int v = (tid < 160) ? bsums[tid] : 0;
    lds[tid] = v;
    __syncthreads();
    for (int d = 1; d < 256; d <<= 1) {
        int t = (tid >= d) ? lds[tid - d] : 0;
        __syncthreads();
        lds[tid] += t;
        __syncthreads();
    }
    bsums[tid] = tid ? lds[tid - 1] : 0;
}

// fixup: rowptrG (global cumulative), cur (insert cursors), inv (1/max(deg,1))
__global__ __launch_bounds__(256)
void scan_fix(const int* __restrict__ icnt, const int* __restrict__ scanbuf,
              const int* __restrict__ bsums, int* __restrict__ rowptrG,
              int* __restrict__ cur, float* __restrict__ inv)
{
    int idx = blockIdx.x * blockDim.x + threadIdx.x;
    if (idx > 163000) return;
    int G = bsums[idx >> 10] + ((idx & 1023) ? scanbuf[idx - 1] : 0);
    rowptrG[idx] = G;
    if (idx < 163000) {
        cur[idx] = G;
        inv[idx] = 1.0f / (float)max(icnt[idx], 1);
    }
}

// ---------------------------------------------------------------- CSR fill (all rels, 1 launch)
__global__ void fill_all(Graph g, int* __restrict__ cur, int* __restrict__ csr)
{
    for (int e = blockIdx.x * blockDim.x + threadIdx.x; e < 2500000; e += gridDim.x * blockDim.x) {
        int r = relof_e(e);
        const int *sp, *dp; relptrs(g, r, sp, dp);
        int le = e - eoff_of(r);
        int gidx = coff_of(r) + dp[le];
        csr[atomicAdd(&cur[gidx], 1)] = sp[le];
    }
}

// ---------------------------------------------------------------- f32 -> bf16 bulk convert
__global__ void tob16_kernel(const float* __restrict__ in, unsigned short* __restrict__ out, int n4)
{
    for (int i = blockIdx.x * blockDim.x + threadIdx.x; i < n4; i += gridDim.x * blockDim.x) {
        float4 v = ((const float4*)in)[i];
        uint2 o;
        o.x = (unsigned int)f2b(v.x) | ((unsigned int)f2b(v.y) << 16);
        o.y = (unsigned int)f2b(v.z) | ((unsigned int)f2b(v.w) << 16);
        ((uint2*)out)[i] = o;
    }
}

// ---------------------------------------------------------------- fused gather-mean, all relations in one launch
struct GatherCfg {
    const unsigned short* X[7];
    const int* rowptrG;
    const int* csr;
    const float* inv;
    unsigned short* agg;
};

template <int D>
__global__ __launch_bounds__(256)
void gather_all(GatherCfg c)
{
    constexpr int LPE = D / 8;        // lanes per edge (one uint4 = 16B each)
    constexpr int EPW = 64 / LPE;     // edges per wave-iteration
    int wid = (blockIdx.x * blockDim.x + threadIdx.x) >> 6;
    if (wid >= 163000) return;
    int l = threadIdx.x & 63;
    int q = l & (LPE - 1);
    int gg = l / LPE;
    int r = relof_n(wid);
    const unsigned short* X = c.X[0];
    if (r==1) X=c.X[1];
    if (r==2) X=c.X[2];
    if (r==3) X=c.X[3];
    if (r==4) X=c.X[4];
    if (r==5) X=c.X[5];
    if (r==6) X=c.X[6];
    const unsigned short* Xq = X + q * 8;
    const int* csr = c.csr;
    int beg = c.rowptrG[wid], end = c.rowptrG[wid + 1];
    float acc[8] = {0.f,0.f,0.f,0.f,0.f,0.f,0.f,0.f};
    int it = beg;
    for (; it + 2 * EPW <= end; it += 2 * EPW) {
        int s0 = csr[it + gg];
        int s1 = csr[it + EPW + gg];
        uint4 v0 = *(const uint4*)(Xq + (size_t)s0 * D);
        uint4 v1 = *(const uint4*)(Xq + (size_t)s1 * D);
        acc[0]+=blo(v0.x); acc[1]+=bhi(v0.x); acc[2]+=blo(v0.y); acc[3]+=bhi(v0.y);
        acc[4]+=blo(v0.z); acc[5]+=bhi(v0.z); acc[6]+=blo(v0.w); acc[7]+=bhi(v0.w);
        acc[0]+=blo(v1.x); acc[1]+=bhi(v1.x); acc[2]+=blo(v1.y); acc[3]+=bhi(v1.y);
        acc[4]+=blo(v1.z); acc[5]+=bhi(v1.z); acc[6]+=blo(v1.w); acc[7]+=bhi(v1.w);
    }
    for (; it < end; it += EPW) {
        int i0 = it + gg;
        if (i0 < end) {
            int s0 = csr[i0];
            uint4 v0 = *(const uint4*)(Xq + (size_t)s0 * D);
            acc[0]+=blo(v0.x); acc[1]+=bhi(v0.x); acc[2]+=blo(v0.y); acc[3]+=bhi(v0.y);
            acc[4]+=blo(v0.z); acc[5]+=bhi(v0.z); acc[6]+=blo(v0.w); acc[7]+=bhi(v0.w);
        }
    }
#pragma unroll
    for (int k = 0; k < 8; ++k) {
        if (LPE == 16) acc[k] += __shfl_xor(acc[k], 16);
        acc[k] += __shfl_xor(acc[k], 32);
    }
    if (l < LPE) {
        float inv = c.inv[wid];
        uint4 o;
        o.x = (unsigned int)f2b(acc[0]*inv) | ((unsigned int)f2b(acc[1]*inv) << 16);
        o.y = (unsigned int)f2b(acc[2]*inv) | ((unsigned int)f2b(acc[3]*inv) << 16);
        o.z = (unsigned int)f2b(acc[4]*inv) | ((unsigned int)f2b(acc[5]*inv) << 16);
        o.w = (unsigned int)f2b(acc[6]*inv) | ((unsigned int)f2b(acc[7]*inv) << 16);
        *(uint4*)(c.agg + (size_t)wid * D + q * 8) = o;
    }
}

// ---------------------------------------------------------------- weight prep: sum roots, transpose to [N][K] bf16
// (biases dropped: a per-column constant cancels exactly in train-mode BN's v - mu)
__global__ void wtrans_kernel(const float* __restrict__ Wr, const float* __restrict__ Wl,
                              unsigned short* __restrict__ wsumT, unsigned short* __restrict__ WlT,
                              int K)
{
    const int nrel[4]  = {2, 2, 2, 1};
    const int rl[4][2] = {{4,5},{1,6},{0,3},{2,2}};
    int per = 256 * K;
    int tot = 11 * per;
    for (int idx = blockIdx.x * blockDim.x + threadIdx.x; idx < tot;
         idx += gridDim.x * blockDim.x) {
        if (idx < 4 * per) {
            int t = idx / per, rem = idx - t * per;
            int n = rem / K, k = rem - n * K;
            float s = Wr[(size_t)rl[t][0] * per + k * 256 + n];
            if (nrel[t] > 1) s += Wr[(size_t)rl[t][1] * per + k * 256 + n];
            wsumT[idx] = f2b(s);
        } else {
            int j = idx - 4 * per;
            int r = j / per, rem = j - r * per;
            int n = rem / K, k = rem - n * K;
            WlT[j] = f2b(Wl[(size_t)r * per + k * 256 + n]);
        }
    }
}

// ---------------------------------------------------------------- fused MFMA GEMM, all 4 types in one launch
struct GemmBatch {
    const unsigned short* A0[4];
    const unsigned short* A1[4];
    const unsigned short* A2[4];
    const unsigned short* B0[4];
    const unsigned short* B1[4];
    const unsigned short* B2[4];
    float* outF;
    unsigned short* outB;
    int R[4]; int bcum[4]; int rowoff[4]; int nsrc[4];
    int K, kshift, outf32;
};

__global__ __launch_bounds__(256)
void gemm_mfma(GemmBatch g)
{
    __shared__ __align__(16) unsigned short Atile[2][128 * 32];
    __shared__ __align__(16) unsigned short Btile[2][128 * 32];

    const int tid = threadIdx.x;
    const int bz = blockIdx.x;
    const int t = (bz >= g.bcum[1]) + (bz >= g.bcum[2]) + (bz >= g.bcum[3]);
    const int bm = (bz - g.bcum[t]) << 7;
    const int bn = blockIdx.y << 7;
    const int w = tid >> 6, l = tid & 63;
    const int wr = w >> 1, wc = w & 1;

    const int R = g.R[t];
    const int K = g.K, kshift = g.kshift, kmask = K - 1;
    const unsigned short* A0t = g.A0[t];
    const unsigned short* A1t = g.A1[t];
    const unsigned short* A2t = g.A2[t];
    const unsigned short* B0t = g.B0[t];
    const unsigned short* B1t = g.B1[t];
    const unsigned short* B2t = g.B2[t];
    const int steps = (g.nsrc[t] * K) >> 5;

    const int ar0 = tid >> 2,          ac0 = tid & 3;
    const int ar1 = (tid + 256) >> 2,  ac1 = (tid + 256) & 3;
    const int wA0 = ar0 * 32 + ((ac0 ^ ((ar0 >> 1) & 3)) << 3);
    const int wA1 = ar1 * 32 + ((ac1 ^ ((ar1 >> 1) & 3)) << 3);

    uint4 rA0, rA1, rB0, rB1;
    auto stage_load = [&](int st) {
        int kglob = st << 5;
        int s  = kglob >> kshift;
        int kk = kglob & kmask;
        const unsigned short* As = (s == 0) ? A0t : (s == 1) ? A1t : A2t;
        const unsigned short* Bs = (s == 0) ? B0t : (s == 1) ? B1t : B2t;
        uint4 z; z.x = z.y = z.z = z.w = 0u;
        int r0 = bm + ar0, r1 = bm + ar1;
        rA0 = (r0 < R) ? *(const uint4*)(As + (size_t)r0 * K + kk + ac0 * 8) : z;
        rA1 = (r1 < R) ? *(const uint4*)(As + (size_t)r1 * K + kk + ac1 * 8) : z;
        rB0 = *(const uint4*)(Bs + (size_t)(bn + ar0) * K + kk + ac0 * 8);
        rB1 = *(const uint4*)(Bs + (size_t)(bn + ar1) * K + kk + ac1 * 8);
    };
    auto stage_write = [&](int st) {
        unsigned short* At = Atile[st & 1];
        unsigned short* Bt = Btile[st & 1];
        *(uint4*)(At + wA0) = rA0;
        *(uint4*)(At + wA1) = rA1;
        *(uint4*)(Bt + wA0) = rB0;
        *(uint4*)(Bt + wA1) = rB1;
    };

    f32x4 acc[4][4];
#pragma unroll
    for (int i = 0; i < 4; ++i)
#pragma unroll
        for (int j = 0; j < 4; ++j)
            acc[i][j] = (f32x4){0.f, 0.f, 0.f, 0.f};

    const int ra = wr * 64 + (l & 15);
    const int rb = wc * 64 + (l & 15);
    const int ck = l >> 4;
    const int aoff = ra * 32 + ((ck ^ ((ra >> 1) & 3)) << 3);
    const int boff = rb * 32 + ((ck ^ ((rb >> 1) & 3)) << 3);

    stage_load(0);
    stage_write(0);
    for (int st = 0; st < steps; ++st) {
        __syncthreads();
        if (st + 1 < steps) stage_load(st + 1);
        const unsigned short* At = Atile[st & 1];
        const unsigned short* Bt = Btile[st & 1];
        bf16x8 af[4], bfr[4];
#pragma unroll
        for (int i = 0; i < 4; ++i) {
            af[i]  = *(const bf16x8*)(At + aoff + i * 512);
            bfr[i] = *(const bf16x8*)(Bt + boff + i * 512);
        }
#pragma unroll
        for (int mi = 0; mi < 4; ++mi)
#pragma unroll
            for (int ni = 0; ni < 4; ++ni)
                acc[mi][ni] = __builtin_amdgcn_mfma_f32_16x16x32_bf16(
                    af[mi], bfr[ni], acc[mi][ni], 0, 0, 0);
        if (st + 1 < steps) stage_write(st + 1);
    }

    const int orow0 = bm + wr * 64 + ((l >> 4) << 2);
    const int ocol0 = bn + wc * 64 + (l & 15);
#pragma unroll
    for (int ni = 0; ni < 4; ++ni) {
        int col = ocol0 + ni * 16;
#pragma unroll
        for (int mi = 0; mi < 4; ++mi) {
#pragma unroll
            for (int j = 0; j < 4; ++j) {
                int row = orow0 + mi * 16 + j;
                if (row < R) {
                    float v = acc[mi][ni][j];
                    size_t o = (size_t)(g.rowoff[t] + row) * 256 + col;
                    if (g.outf32) g.outF[o] = v;
                    else          g.outB[o] = f2b(v);
                }
            }
        }
    }
}

// ---------------------------------------------------------------- BatchNorm (train-mode) + ReLU, all types fused
template <int F32>
__global__ __launch_bounds__(256)
void bn_stats_all(const void* __restrict__ Hv, float* __restrict__ stats)
{
    int c = threadIdx.x;
    int r0 = blockIdx.x * 128;
    int r1 = min(r0 + 128, 83000);
    int t = typ_of(r0);
    int nb = nbound(t);
    float s = 0.f, ss = 0.f;
    for (int r = r0; r < r1; ++r) {
        if (r == nb) {
            atomicAdd(&stats[t * 512 + c], s);
            atomicAdd(&stats[t * 512 + 256 + c], ss);
            s = ss = 0.f; ++t; nb = nbound(t);
        }
        float v;
        if (F32) v = ((const float*)Hv)[(size_t)r * 256 + c];
        else { unsigned int u = ((const unsigned short*)Hv)[(size_t)r * 256 + c]; v = blo(u); }
        s += v; ss += v * v;
    }
    atomicAdd(&stats[t * 512 + c], s);
    atomicAdd(&stats[t * 512 + 256 + c], ss);
}

template <int F32>
__global__ __launch_bounds__(256)
void bn_apply_all(void* __restrict__ Hv, const float* __restrict__ stats,
                  const float* __restrict__ gg, const float* __restrict__ be)
{
    const int total4 = 83000 * 64;
    for (int i4 = blockIdx.x * blockDim.x + threadIdx.x; i4 < total4;
         i4 += gridDim.x * blockDim.x) {
        int row = i4 >> 6;
        int c4  = (i4 & 63) << 2;
        int t   = typ_of(row);
        float invR = invR_of(t);
        const float* st = stats + t * 512;
        float vin[4];
        if (F32) {
            float4 v = *(const float4*)((const float*)Hv + (size_t)row * 256 + c4);
            vin[0]=v.x; vin[1]=v.y; vin[2]=v.z; vin[3]=v.w;
        } else {
            uint2 u = *(const uint2*)((const unsigned short*)Hv + (size_t)row * 256 + c4);
            vin[0]=blo(u.x); vin[1]=bhi(u.x); vin[2]=blo(u.y); vin[3]=bhi(u.y);
        }
        float vout[4];
#pragma unroll
        for (int k = 0; k < 4; ++k) {
            int c = c4 + k;
            float mu  = st[c] * invR;
            float var = st[256 + c] * invR - mu * mu;
            float sc  = rsqrtf(var + EPS_BN) * gg[c];
            float v   = (vin[k] - mu) * sc + be[c];
            vout[k] = fmaxf(v, 0.f);
        }
        if (F32) {
            float4 o; o.x=vout[0]; o.y=vout[1]; o.z=vout[2]; o.w=vout[3];
            *(float4*)((float*)Hv + (size_t)row * 256 + c4) = o;
        } else {
            uint2 o;
            o.x = (unsigned int)f2b(vout[0]) | ((unsigned int)f2b(vout[1]) << 16);
            o.y = (unsigned int)f2b(vout[2]) | ((unsigned int)f2b(vout[3]) << 16);
            *(uint2*)((unsigned short*)Hv + (size_t)row * 256 + c4) = o;
        }
    }
}

// ---------------------------------------------------------------- host
extern "C" void kernel_launch(void* const* d_in, const int* in_sizes, int n_in,
                              void* d_out, int out_size, void* d_ws, size_t ws_size,
                              hipStream_t stream)
{
    static const int Nn[4]   = {20000, 50000, 10000, 3000};
    static const int roff[4] = {0, 20000, 70000, 80000};
    static const int rst[7]  = {0, 0, 1, 1, 2, 1, 3};
    static const int coff[7] = {0, 10000, 60000, 63000, 73000, 93000, 113000};
    static const int trels[4][2] = {{4,5},{1,6},{0,3},{2,2}};
    static const int tnrel[4]    = {2, 2, 2, 1};
    const int CNT_TOTAL = 163000;

    const float* x[4];
    for (int t = 0; t < 4; ++t) x[t] = (const float*)d_in[t];
    Graph graph;
    for (int i = 0; i < 7; ++i) {
        graph.src[i] = (const int*)d_in[4 + 2 * i];
        graph.dst[i] = (const int*)d_in[5 + 2 * i];
    }
    const float* W1l = (const float*)d_in[18];
    const float* W1r = (const float*)d_in[19];
    const float* W2l = (const float*)d_in[21];
    const float* W2r = (const float*)d_in[22];
    const float* g1  = (const float*)d_in[24];
    const float* be1 = (const float*)d_in[25];
    const float* g2  = (const float*)d_in[26];
    const float* be2 = (const float*)d_in[27];
    float* out = (float*)d_out;
    (void)n_in; (void)in_sizes; (void)out_size; (void)ws_size;

    // ---- workspace carve (~141 MB)
    char* w = (char*)d_ws;
    size_t off = 0;
    auto carve = [&](size_t bytes) -> void* {
        void* p = (void*)(w + off);
        off = (off + bytes + 255) & ~(size_t)255;
        return p;
    };
    int*   icnt    = (int*)carve((size_t)CNT_TOTAL * 4);
    int*   cur     = (int*)carve((size_t)CNT_TOTAL * 4);
    int*   rowptrG = (int*)carve((size_t)(CNT_TOTAL + 1) * 4);
    int*   csr     = (int*)carve((size_t)2500000 * 4);
    int*   scanbuf = (int*)carve((size_t)163840 * 4);
    int*   bsums   = (int*)carve((size_t)256 * 4);
    float* inv     = (float*)carve((size_t)CNT_TOTAL * 4);
    float* stats   = (float*)carve((size_t)4 * 512 * 4);
    unsigned short* wsumT = (unsigned short*)carve((size_t)4 * 256 * 256 * 2);
    unsigned short* WlT   = (unsigned short*)carve((size_t)7 * 256 * 256 * 2);
    unsigned short* U     = (unsigned short*)carve((size_t)163000 * 256 * 2); // union region
    unsigned short* hb    = (unsigned short*)carve((size_t)83000 * 256 * 2);
    unsigned short* xb    = U;                        // layer-1: bf16 inputs (21.25 MB)
    unsigned short* aggL1 = U + (size_t)83000 * 128;  // layer-1 agg (after xb)
    unsigned short* aggL2 = U;                        // layer-2 agg (xb dead by then)

    // ---- CSR build (globally-cumulative rowptr; shared by both layers)
    hipMemsetAsync(icnt, 0, (size_t)CNT_TOTAL * 4, stream);
    count_all<<<2048, 256, 0, stream>>>(graph, icnt);
    scan1<<<160, 1024, 0, stream>>>(icnt, scanbuf, bsums);
    scan2<<<1, 256, 0, stream>>>(bsums);
    scan_fix<<<(CNT_TOTAL + 256) / 256, 256, 0, stream>>>(icnt, scanbuf, bsums,
                                                          rowptrG, cur, inv);
    fill_all<<<2048, 256, 0, stream>>>(graph, cur, csr);

    // ---- x -> bf16
    for (int t = 0; t < 4; ++t)
        tob16_kernel<<<512, 256, 0, stream>>>(x[t], xb + (size_t)roff[t] * 128, Nn[t] * 32);

    for (int layer = 0; layer < 2; ++layer) {
        const int K = layer ? 256 : 128;
        const float* Wl = layer ? W2l : W1l;
        const float* Wr = layer ? W2r : W1r;
        const float* gg = layer ? g2  : g1;
        const float* be = layer ? be2 : be1;
        unsigned short* agg = layer ? aggL2 : aggL1;

        wtrans_kernel<<<1024, 256, 0, stream>>>(Wr, Wl, wsumT, WlT, K);

        GatherCfg gc;
        for (int r = 0; r < 7; ++r)
            gc.X[r] = layer ? (hb + (size_t)roff[rst[r]] * 256)
                            : (xb + (size_t)roff[rst[r]] * 128);
        gc.rowptrG = rowptrG; gc.csr = csr; gc.inv = inv; gc.agg = agg;
        if (layer == 0) gather_all<128><<<40750, 256, 0, stream>>>(gc);
        else            gather_all<256><<<40750, 256, 0, stream>>>(gc);

        GemmBatch gb;
        for (int t = 0; t < 4; ++t) {
            gb.A0[t] = layer ? (hb + (size_t)roff[t] * 256) : (xb + (size_t)roff[t] * 128);
            gb.A1[t] = agg + (size_t)coff[trels[t][0]] * K;
            gb.A2[t] = (tnrel[t] > 1) ? (agg + (size_t)coff[trels[t][1]] * K) : gb.A1[t];
            gb.B0[t] = wsumT + (size_t)t * 256 * K;
            gb.B1[t] = WlT + (size_t)trels[t][0] * 256 * K;
            gb.B2[t] = (tnrel[t] > 1) ? (WlT + (size_t)trels[t][1] * 256 * K) : gb.B1[t];
            gb.R[t] = Nn[t];
            gb.rowoff[t] = roff[t];
            gb.nsrc[t] = 1 + tnrel[t];
        }
        gb.bcum[0] = 0; gb.bcum[1] = 157; gb.bcum[2] = 548; gb.bcum[3] = 627;
        gb.outF = out; gb.outB = hb;
        gb.K = K; gb.kshift = layer ? 8 : 7; gb.outf32 = layer;
        gemm_mfma<<<dim3(651, 2), 256, 0, stream>>>(gb);

        hipMemsetAsync(stats, 0, (size_t)4 * 512 * 4, stream);
        if (layer == 0) {
            bn_stats_all<0><<<649, 256, 0, stream>>>(hb, stats);
            bn_apply_all<0><<<2048, 256, 0, stream>>>(hb, stats, gg, be);
        } else {
            bn_stats_all<1><<<649, 256, 0, stream>>>(out, stats);
            bn_apply_all<1><<<2048, 256, 0, stream>>>(out, stats, gg, be);
        }
    }
}

// Round 5
// 1130.543 us; speedup vs baseline: 4.2569x; 1.0518x over previous
//
#include <hip/hip_runtime.h>

#define EPS_BN 1e-5f

typedef short bf16x8 __attribute__((ext_vector_type(8)));
typedef float f32x4 __attribute__((ext_vector_type(4)));

__device__ __forceinline__ unsigned short f2b(float f)
{
    union { float f; unsigned int u; } c; c.f = f;
    unsigned int u = c.u + 0x7FFFu + ((c.u >> 16) & 1u);
    return (unsigned short)(u >> 16);
}
__device__ __forceinline__ float blo(unsigned int u)
{
    union { unsigned int u; float f; } c; c.u = u << 16; return c.f;
}
__device__ __forceinline__ float bhi(unsigned int u)
{
    union { unsigned int u; float f; } c; c.u = u & 0xFFFF0000u; return c.f;
}

// relation / type index helpers (branchless compare-sums)
__device__ __forceinline__ int relof_e(int e) {
    return (e>=500000)+(e>=900000)+(e>=1050000)+(e>=1450000)+(e>=1950000)+(e>=2350000);
}
__device__ __forceinline__ int relof_n(int i) {
    return (i>=10000)+(i>=60000)+(i>=63000)+(i>=73000)+(i>=93000)+(i>=113000);
}
__device__ __forceinline__ int eoff_of(int r) {
    return r<1?0 : r<2?500000 : r<3?900000 : r<4?1050000 : r<5?1450000 : r<6?1950000 : 2350000;
}
__device__ __forceinline__ int coff_of(int r) {
    return r<1?0 : r<2?10000 : r<3?60000 : r<4?63000 : r<5?73000 : r<6?93000 : 113000;
}
__device__ __forceinline__ int typ_of(int row) { return (row>=20000)+(row>=70000)+(row>=80000); }
__device__ __forceinline__ int nbound(int t)   { return t<1?20000 : t<2?70000 : t<3?80000 : 83000; }
__device__ __forceinline__ float invR_of(int t){ return t<1?5e-5f : t<2?2e-5f : t<3?1e-4f : (1.0f/3000.0f); }

struct Graph { const int* src[7]; const int* dst[7]; };

__device__ __forceinline__ void relptrs(const Graph& g, int r, const int*& sp, const int*& dp)
{
    sp = g.src[0]; dp = g.dst[0];
    if (r==1){sp=g.src[1];dp=g.dst[1];}
    if (r==2){sp=g.src[2];dp=g.dst[2];}
    if (r==3){sp=g.src[3];dp=g.dst[3];}
    if (r==4){sp=g.src[4];dp=g.dst[4];}
    if (r==5){sp=g.src[5];dp=g.dst[5];}
    if (r==6){sp=g.src[6];dp=g.dst[6];}
}

// ---------------------------------------------------------------- degree histogram (all rels, 1 launch)
__global__ void count_all(Graph g, int* __restrict__ icnt)
{
    for (int e = blockIdx.x * blockDim.x + threadIdx.x; e < 2500000; e += gridDim.x * blockDim.x) {
        int r = relof_e(e);
        const int *sp, *dp; relptrs(g, r, sp, dp);
        int le = e - eoff_of(r);
        atomicAdd(&icnt[coff_of(r) + dp[le]], 1);
    }
}

// ---------------------------------------------------------------- 3-phase global scan
__global__ __launch_bounds__(1024)
void scan1(const int* __restrict__ icnt, int* __restrict__ scanbuf, int* __restrict__ bsums)
{
    __shared__ int lds[1024];
    int tid = threadIdx.x;
    int gid = blockIdx.x * 1024 + tid;
    int v = (gid < 163000) ? icnt[gid] : 0;
    lds[tid] = v;
    __syncthreads();
    for (int d = 1; d < 1024; d <<= 1) {
        int t = (tid >= d) ? lds[tid - d] : 0;
        __syncthreads();
        lds[tid] += t;
        __syncthreads();
    }
    scanbuf[gid] = lds[tid];                  // inclusive within block
    if (tid == 1023) bsums[blockIdx.x] = lds[1023];
}

__global__ __launch_bounds__(256)
void scan2(int* __restrict__ bsums)          // exclusive scan of 160 partials, in place
{
    __shared__ int lds[256];
    int tid = threadIdx.x;
    int v = (tid < 160) ? bsums[tid] : 0;
    lds[tid] = v;
    __syncthreads();
    for (int d = 1; d < 256; d <<= 1) {
        int t = (tid >= d) ? lds[tid - d] : 0;
        __syncthreads();
        lds[tid] += t;
        __syncthreads();
    }
    bsums[tid] = tid ? lds[tid - 1] : 0;
}

// fixup: rowptrG (global cumulative), cur (insert cursors), inv (1/max(deg,1))
__global__ __launch_bounds__(256)
void scan_fix(const int* __restrict__ icnt, const int* __restrict__ scanbuf,
              const int* __restrict__ bsums, int* __restrict__ rowptrG,
              int* __restrict__ cur, float* __restrict__ inv)
{
    int idx = blockIdx.x * blockDim.x + threadIdx.x;
    if (idx > 163000) return;
    int G = bsums[idx >> 10] + ((idx & 1023) ? scanbuf[idx - 1] : 0);
    rowptrG[idx] = G;
    if (idx < 163000) {
        cur[idx] = G;
        inv[idx] = 1.0f / (float)max(icnt[idx], 1);
    }
}

// ---------------------------------------------------------------- CSR fill (all rels, 1 launch)
__global__ void fill_all(Graph g, int* __restrict__ cur, int* __restrict__ csr)
{
    for (int e = blockIdx.x * blockDim.x + threadIdx.x; e < 2500000; e += gridDim.x * blockDim.x) {
        int r = relof_e(e);
        const int *sp, *dp; relptrs(g, r, sp, dp);
        int le = e - eoff_of(r);
        int gidx = coff_of(r) + dp[le];
        csr[atomicAdd(&cur[gidx], 1)] = sp[le];
    }
}

// ---------------------------------------------------------------- f32 -> bf16 bulk convert
__global__ void tob16_kernel(const float* __restrict__ in, unsigned short* __restrict__ out, int n4)
{
    for (int i = blockIdx.x * blockDim.x + threadIdx.x; i < n4; i += gridDim.x * blockDim.x) {
        float4 v = ((const float4*)in)[i];
        uint2 o;
        o.x = (unsigned int)f2b(v.x) | ((unsigned int)f2b(v.y) << 16);
        o.y = (unsigned int)f2b(v.z) | ((unsigned int)f2b(v.w) << 16);
        ((uint2*)out)[i] = o;
    }
}

// ---------------------------------------------------------------- fused gather-mean, all relations in one launch
struct GatherCfg {
    const unsigned short* X[7];
    const int* rowptrG;
    const int* csr;
    const float* inv;
    unsigned short* agg;
};

template <int D>
__global__ __launch_bounds__(256)
void gather_all(GatherCfg c)
{
    constexpr int LPE = D / 8;        // lanes per edge (one uint4 = 16B each)
    constexpr int EPW = 64 / LPE;     // edges per wave-iteration
    int wid = (blockIdx.x * blockDim.x + threadIdx.x) >> 6;
    if (wid >= 163000) return;
    int l = threadIdx.x & 63;
    int q = l & (LPE - 1);
    int gg = l / LPE;
    int r = relof_n(wid);
    const unsigned short* X = c.X[0];
    if (r==1) X=c.X[1];
    if (r==2) X=c.X[2];
    if (r==3) X=c.X[3];
    if (r==4) X=c.X[4];
    if (r==5) X=c.X[5];
    if (r==6) X=c.X[6];
    const unsigned short* Xq = X + q * 8;
    const int* csr = c.csr;
    int beg = c.rowptrG[wid], end = c.rowptrG[wid + 1];
    float acc[8] = {0.f,0.f,0.f,0.f,0.f,0.f,0.f,0.f};
    int it = beg;
    for (; it + 2 * EPW <= end; it += 2 * EPW) {
        int s0 = csr[it + gg];
        int s1 = csr[it + EPW + gg];
        uint4 v0 = *(const uint4*)(Xq + (size_t)s0 * D);
        uint4 v1 = *(const uint4*)(Xq + (size_t)s1 * D);
        acc[0]+=blo(v0.x); acc[1]+=bhi(v0.x); acc[2]+=blo(v0.y); acc[3]+=bhi(v0.y);
        acc[4]+=blo(v0.z); acc[5]+=bhi(v0.z); acc[6]+=blo(v0.w); acc[7]+=bhi(v0.w);
        acc[0]+=blo(v1.x); acc[1]+=bhi(v1.x); acc[2]+=blo(v1.y); acc[3]+=bhi(v1.y);
        acc[4]+=blo(v1.z); acc[5]+=bhi(v1.z); acc[6]+=blo(v1.w); acc[7]+=bhi(v1.w);
    }
    for (; it < end; it += EPW) {
        int i0 = it + gg;
        if (i0 < end) {
            int s0 = csr[i0];
            uint4 v0 = *(const uint4*)(Xq + (size_t)s0 * D);
            acc[0]+=blo(v0.x); acc[1]+=bhi(v0.x); acc[2]+=blo(v0.y); acc[3]+=bhi(v0.y);
            acc[4]+=blo(v0.z); acc[5]+=bhi(v0.z); acc[6]+=blo(v0.w); acc[7]+=bhi(v0.w);
        }
    }
#pragma unroll
    for (int k = 0; k < 8; ++k) {
        if (LPE == 16) acc[k] += __shfl_xor(acc[k], 16);
        acc[k] += __shfl_xor(acc[k], 32);
    }
    if (l < LPE) {
        float inv = c.inv[wid];
        uint4 o;
        o.x = (unsigned int)f2b(acc[0]*inv) | ((unsigned int)f2b(acc[1]*inv) << 16);
        o.y = (unsigned int)f2b(acc[2]*inv) | ((unsigned int)f2b(acc[3]*inv) << 16);
        o.z = (unsigned int)f2b(acc[4]*inv) | ((unsigned int)f2b(acc[5]*inv) << 16);
        o.w = (unsigned int)f2b(acc[6]*inv) | ((unsigned int)f2b(acc[7]*inv) << 16);
        *(uint4*)(c.agg + (size_t)wid * D + q * 8) = o;
    }
}

// ---------------------------------------------------------------- weight prep: sum roots, transpose to [N][K] bf16
// (biases dropped: a per-column constant cancels exactly in train-mode BN's v - mu)
__global__ void wtrans_kernel(const float* __restrict__ Wr, const float* __restrict__ Wl,
                              unsigned short* __restrict__ wsumT, unsigned short* __restrict__ WlT,
                              int K)
{
    const int nrel[4]  = {2, 2, 2, 1};
    const int rl[4][2] = {{4,5},{1,6},{0,3},{2,2}};
    int per = 256 * K;
    int tot = 11 * per;
    for (int idx = blockIdx.x * blockDim.x + threadIdx.x; idx < tot;
         idx += gridDim.x * blockDim.x) {
        if (idx < 4 * per) {
            int t = idx / per, rem = idx - t * per;
            int n = rem / K, k = rem - n * K;
            float s = Wr[(size_t)rl[t][0] * per + k * 256 + n];
            if (nrel[t] > 1) s += Wr[(size_t)rl[t][1] * per + k * 256 + n];
            wsumT[idx] = f2b(s);
        } else {
            int j = idx - 4 * per;
            int r = j / per, rem = j - r * per;
            int n = rem / K, k = rem - n * K;
            WlT[j] = f2b(Wl[(size_t)r * per + k * 256 + n]);
        }
    }
}

// ---------------------------------------------------------------- fused MFMA GEMM, 128x256 blocks, all types in one launch
struct GemmBatch {
    const unsigned short* A0[4];
    const unsigned short* A1[4];
    const unsigned short* A2[4];
    const unsigned short* B0[4];
    const unsigned short* B1[4];
    const unsigned short* B2[4];
    float* outF;
    unsigned short* outB;
    int R[4]; int bcum[4]; int rowoff[4]; int nsrc[4];
    int K, kshift, outf32;
};

__global__ __launch_bounds__(256)
void gemm_mfma(GemmBatch g)
{
    __shared__ __align__(16) unsigned short Atile[2][128 * 32];   // 16 KB
    __shared__ __align__(16) unsigned short Btile[2][256 * 32];   // 32 KB

    const int tid = threadIdx.x;
    const int bz = blockIdx.x;
    const int t = (bz >= g.bcum[1]) + (bz >= g.bcum[2]) + (bz >= g.bcum[3]);
    const int bm = (bz - g.bcum[t]) << 7;
    const int w = tid >> 6, l = tid & 63;
    const int wr = w >> 1, wc = w & 1;          // 2x2 waves, wave tile 64 rows x 128 cols

    const int R = g.R[t];
    const int K = g.K, kshift = g.kshift, kmask = K - 1;
    const unsigned short* A0t = g.A0[t];
    const unsigned short* A1t = g.A1[t];
    const unsigned short* A2t = g.A2[t];
    const unsigned short* B0t = g.B0[t];
    const unsigned short* B1t = g.B1[t];
    const unsigned short* B2t = g.B2[t];
    const int steps = (g.nsrc[t] * K) >> 5;

    // staging: A = 512 chunks (2/thread), B = 1024 chunks (4/thread)
    const int ar0 = tid >> 2, ac = tid & 3;
    const int swzsh = (ac << 3);   // base chunk offset in ushorts (before row-xor)
    auto wadr = [&](int row) { return row * 32 + (((ac ^ ((row >> 1) & 3))) << 3); };
    const int wA0 = wadr(ar0);
    const int wA1 = wadr(ar0 + 64);
    const int wB0 = wA0;
    const int wB1 = wA1;
    const int wB2 = wadr(ar0 + 128);
    const int wB3 = wadr(ar0 + 192);

    uint4 rA0, rA1, rB0, rB1, rB2, rB3;
    auto stage_load = [&](int st) {
        int kglob = st << 5;
        int s  = kglob >> kshift;
        int kk = kglob & kmask;
        const unsigned short* As = (s == 0) ? A0t : (s == 1) ? A1t : A2t;
        const unsigned short* Bs = (s == 0) ? B0t : (s == 1) ? B1t : B2t;
        uint4 z; z.x = z.y = z.z = z.w = 0u;
        int r0 = bm + ar0, r1 = bm + ar0 + 64;
        rA0 = (r0 < R) ? *(const uint4*)(As + (size_t)r0 * K + kk + ac * 8) : z;
        rA1 = (r1 < R) ? *(const uint4*)(As + (size_t)r1 * K + kk + ac * 8) : z;
        rB0 = *(const uint4*)(Bs + (size_t)(ar0      ) * K + kk + ac * 8);
        rB1 = *(const uint4*)(Bs + (size_t)(ar0 +  64) * K + kk + ac * 8);
        rB2 = *(const uint4*)(Bs + (size_t)(ar0 + 128) * K + kk + ac * 8);
        rB3 = *(const uint4*)(Bs + (size_t)(ar0 + 192) * K + kk + ac * 8);
    };
    auto stage_write = [&](int st) {
        unsigned short* At = Atile[st & 1];
        unsigned short* Bt = Btile[st & 1];
        *(uint4*)(At + wA0) = rA0;
        *(uint4*)(At + wA1) = rA1;
        *(uint4*)(Bt + wB0) = rB0;
        *(uint4*)(Bt + wB1) = rB1;
        *(uint4*)(Bt + wB2) = rB2;
        *(uint4*)(Bt + wB3) = rB3;
    };

    f32x4 acc[4][8];
#pragma unroll
    for (int i = 0; i < 4; ++i)
#pragma unroll
        for (int j = 0; j < 8; ++j)
            acc[i][j] = (f32x4){0.f, 0.f, 0.f, 0.f};

    const int ck = l >> 4;
    const int ra = wr * 64 + (l & 15);
    const int aoff = ra * 32 + ((ck ^ ((ra >> 1) & 3)) << 3);
    const int rb = wc * 128 + (l & 15);
    const int boff = rb * 32 + ((ck ^ ((rb >> 1) & 3)) << 3);   // 16-row frag steps keep (row>>1)&3 invariant

    stage_load(0);
    stage_write(0);
    for (int st = 0; st < steps; ++st) {
        __syncthreads();
        if (st + 1 < steps) stage_load(st + 1);
        const unsigned short* At = Atile[st & 1];
        const unsigned short* Bt = Btile[st & 1];
        bf16x8 af[4];
#pragma unroll
        for (int i = 0; i < 4; ++i)
            af[i] = *(const bf16x8*)(At + aoff + i * 512);
#pragma unroll
        for (int nh = 0; nh < 2; ++nh) {
            bf16x8 bfr[4];
#pragma unroll
            for (int i = 0; i < 4; ++i)
                bfr[i] = *(const bf16x8*)(Bt + boff + nh * 2048 + i * 512);
#pragma unroll
            for (int mi = 0; mi < 4; ++mi)
#pragma unroll
                for (int ni = 0; ni < 4; ++ni)
                    acc[mi][nh * 4 + ni] = __builtin_amdgcn_mfma_f32_16x16x32_bf16(
                        af[mi], bfr[ni], acc[mi][nh * 4 + ni], 0, 0, 0);
        }
        if (st + 1 < steps) stage_write(st + 1);
    }

    const int orow0 = bm + wr * 64 + ((l >> 4) << 2);
    const int ocol0 = wc * 128 + (l & 15);
#pragma unroll
    for (int nf = 0; nf < 8; ++nf) {
        int col = ocol0 + nf * 16;
#pragma unroll
        for (int mi = 0; mi < 4; ++mi) {
#pragma unroll
            for (int j = 0; j < 4; ++j) {
                int row = orow0 + mi * 16 + j;
                if (row < R) {
                    float v = acc[mi][nf][j];
                    size_t o = (size_t)(g.rowoff[t] + row) * 256 + col;
                    if (g.outf32) g.outF[o] = v;
                    else          g.outB[o] = f2b(v);
                }
            }
        }
    }
}

// ---------------------------------------------------------------- BatchNorm (train-mode) + ReLU, all types fused
template <int F32>
__global__ __launch_bounds__(256)
void bn_stats_all(const void* __restrict__ Hv, float* __restrict__ stats)
{
    int c = threadIdx.x;
    int r0 = blockIdx.x * 128;
    int r1 = min(r0 + 128, 83000);
    int t = typ_of(r0);
    int nb = nbound(t);
    float s = 0.f, ss = 0.f;
    for (int r = r0; r < r1; ++r) {
        if (r == nb) {
            atomicAdd(&stats[t * 512 + c], s);
            atomicAdd(&stats[t * 512 + 256 + c], ss);
            s = ss = 0.f; ++t; nb = nbound(t);
        }
        float v;
        if (F32) v = ((const float*)Hv)[(size_t)r * 256 + c];
        else { unsigned int u = ((const unsigned short*)Hv)[(size_t)r * 256 + c]; v = blo(u); }
        s += v; ss += v * v;
    }
    atomicAdd(&stats[t * 512 + c], s);
    atomicAdd(&stats[t * 512 + 256 + c], ss);
}

template <int F32>
__global__ __launch_bounds__(256)
void bn_apply_all(void* __restrict__ Hv, const float* __restrict__ stats,
                  const float* __restrict__ gg, const float* __restrict__ be)
{
    const int total4 = 83000 * 64;
    for (int i4 = blockIdx.x * blockDim.x + threadIdx.x; i4 < total4;
         i4 += gridDim.x * blockDim.x) {
        int row = i4 >> 6;
        int c4  = (i4 & 63) << 2;
        int t   = typ_of(row);
        float invR = invR_of(t);
        const float* st = stats + t * 512;
        float vin[4];
        if (F32) {
            float4 v = *(const float4*)((const float*)Hv + (size_t)row * 256 + c4);
            vin[0]=v.x; vin[1]=v.y; vin[2]=v.z; vin[3]=v.w;
        } else {
            uint2 u = *(const uint2*)((const unsigned short*)Hv + (size_t)row * 256 + c4);
            vin[0]=blo(u.x); vin[1]=bhi(u.x); vin[2]=blo(u.y); vin[3]=bhi(u.y);
        }
        float vout[4];
#pragma unroll
        for (int k = 0; k < 4; ++k) {
            int c = c4 + k;
            float mu  = st[c] * invR;
            float var = st[256 + c] * invR - mu * mu;
            float sc  = rsqrtf(var + EPS_BN) * gg[c];
            float v   = (vin[k] - mu) * sc + be[c];
            vout[k] = fmaxf(v, 0.f);
        }
        if (F32) {
            float4 o; o.x=vout[0]; o.y=vout[1]; o.z=vout[2]; o.w=vout[3];
            *(float4*)((float*)Hv + (size_t)row * 256 + c4) = o;
        } else {
            uint2 o;
            o.x = (unsigned int)f2b(vout[0]) | ((unsigned int)f2b(vout[1]) << 16);
            o.y = (unsigned int)f2b(vout[2]) | ((unsigned int)f2b(vout[3]) << 16);
            *(uint2*)((unsigned short*)Hv + (size_t)row * 256 + c4) = o;
        }
    }
}

// ---------------------------------------------------------------- host
extern "C" void kernel_launch(void* const* d_in, const int* in_sizes, int n_in,
                              void* d_out, int out_size, void* d_ws, size_t ws_size,
                              hipStream_t stream)
{
    static const int Nn[4]   = {20000, 50000, 10000, 3000};
    static const int roff[4] = {0, 20000, 70000, 80000};
    static const int rst[7]  = {0, 0, 1, 1, 2, 1, 3};
    static const int coff[7] = {0, 10000, 60000, 63000, 73000, 93000, 113000};
    static const int trels[4][2] = {{4,5},{1,6},{0,3},{2,2}};
    static const int tnrel[4]    = {2, 2, 2, 1};
    const int CNT_TOTAL = 163000;

    const float* x[4];
    for (int t = 0; t < 4; ++t) x[t] = (const float*)d_in[t];
    Graph graph;
    for (int i = 0; i < 7; ++i) {
        graph.src[i] = (const int*)d_in[4 + 2 * i];
        graph.dst[i] = (const int*)d_in[5 + 2 * i];
    }
    const float* W1l = (const float*)d_in[18];
    const float* W1r = (const float*)d_in[19];
    const float* W2l = (const float*)d_in[21];
    const float* W2r = (const float*)d_in[22];
    const float* g1  = (const float*)d_in[24];
    const float* be1 = (const float*)d_in[25];
    const float* g2  = (const float*)d_in[26];
    const float* be2 = (const float*)d_in[27];
    float* out = (float*)d_out;
    (void)n_in; (void)in_sizes; (void)out_size; (void)ws_size;

    // ---- workspace carve (~141 MB)
    char* w = (char*)d_ws;
    size_t off = 0;
    auto carve = [&](size_t bytes) -> void* {
        void* p = (void*)(w + off);
        off = (off + bytes + 255) & ~(size_t)255;
        return p;
    };
    int*   icnt    = (int*)carve((size_t)CNT_TOTAL * 4);
    int*   cur     = (int*)carve((size_t)CNT_TOTAL * 4);
    int*   rowptrG = (int*)carve((size_t)(CNT_TOTAL + 1) * 4);
    int*   csr     = (int*)carve((size_t)2500000 * 4);
    int*   scanbuf = (int*)carve((size_t)163840 * 4);
    int*   bsums   = (int*)carve((size_t)256 * 4);
    float* inv     = (float*)carve((size_t)CNT_TOTAL * 4);
    float* stats   = (float*)carve((size_t)4 * 512 * 4);
    unsigned short* wsumT = (unsigned short*)carve((size_t)4 * 256 * 256 * 2);
    unsigned short* WlT   = (unsigned short*)carve((size_t)7 * 256 * 256 * 2);
    unsigned short* U     = (unsigned short*)carve((size_t)163000 * 256 * 2); // union region
    unsigned short* hb    = (unsigned short*)carve((size_t)83000 * 256 * 2);
    unsigned short* xb    = U;                        // layer-1: bf16 inputs (21.25 MB)
    unsigned short* aggL1 = U + (size_t)83000 * 128;  // layer-1 agg (after xb)
    unsigned short* aggL2 = U;                        // layer-2 agg (xb dead by then)

    // ---- CSR build (globally-cumulative rowptr; shared by both layers)
    hipMemsetAsync(icnt, 0, (size_t)CNT_TOTAL * 4, stream);
    count_all<<<2048, 256, 0, stream>>>(graph, icnt);
    scan1<<<160, 1024, 0, stream>>>(icnt, scanbuf, bsums);
    scan2<<<1, 256, 0, stream>>>(bsums);
    scan_fix<<<(CNT_TOTAL + 256) / 256, 256, 0, stream>>>(icnt, scanbuf, bsums,
                                                          rowptrG, cur, inv);
    fill_all<<<2048, 256, 0, stream>>>(graph, cur, csr);

    // ---- x -> bf16
    for (int t = 0; t < 4; ++t)
        tob16_kernel<<<512, 256, 0, stream>>>(x[t], xb + (size_t)roff[t] * 128, Nn[t] * 32);

    for (int layer = 0; layer < 2; ++layer) {
        const int K = layer ? 256 : 128;
        const float* Wl = layer ? W2l : W1l;
        const float* Wr = layer ? W2r : W1r;
        const float* gg = layer ? g2  : g1;
        const float* be = layer ? be2 : be1;
        unsigned short* agg = layer ? aggL2 : aggL1;

        wtrans_kernel<<<1024, 256, 0, stream>>>(Wr, Wl, wsumT, WlT, K);

        GatherCfg gc;
        for (int r = 0; r < 7; ++r)
            gc.X[r] = layer ? (hb + (size_t)roff[rst[r]] * 256)
                            : (xb + (size_t)roff[rst[r]] * 128);
        gc.rowptrG = rowptrG; gc.csr = csr; gc.inv = inv; gc.agg = agg;
        if (layer == 0) gather_all<128><<<40750, 256, 0, stream>>>(gc);
        else            gather_all<256><<<40750, 256, 0, stream>>>(gc);

        GemmBatch gb;
        for (int t = 0; t < 4; ++t) {
            gb.A0[t] = layer ? (hb + (size_t)roff[t] * 256) : (xb + (size_t)roff[t] * 128);
            gb.A1[t] = agg + (size_t)coff[trels[t][0]] * K;
            gb.A2[t] = (tnrel[t] > 1) ? (agg + (size_t)coff[trels[t][1]] * K) : gb.A1[t];
            gb.B0[t] = wsumT + (size_t)t * 256 * K;
            gb.B1[t] = WlT + (size_t)trels[t][0] * 256 * K;
            gb.B2[t] = (tnrel[t] > 1) ? (WlT + (size_t)trels[t][1] * 256 * K) : gb.B1[t];
            gb.R[t] = Nn[t];
            gb.rowoff[t] = roff[t];
            gb.nsrc[t] = 1 + tnrel[t];
        }
        gb.bcum[0] = 0; gb.bcum[1] = 157; gb.bcum[2] = 548; gb.bcum[3] = 627;
        gb.outF = out; gb.outB = hb;
        gb.K = K; gb.kshift = layer ? 8 : 7; gb.outf32 = layer;
        gemm_mfma<<<651, 256, 0, stream>>>(gb);

        hipMemsetAsync(stats, 0, (size_t)4 * 512 * 4, stream);
        if (layer == 0) {
            bn_stats_all<0><<<649, 256, 0, stream>>>(hb, stats);
            bn_apply_all<0><<<2048, 256, 0, stream>>>(hb, stats, gg, be);
        } else {
            bn_stats_all<1><<<649, 256, 0, stream>>>(out, stats);
            bn_apply_all<1><<<2048, 256, 0, stream>>>(out, stats, gg, be);
        }
    }
}

// Round 6
// 924.691 us; speedup vs baseline: 5.2046x; 1.2226x over previous
//
#include <hip/hip_runtime.h>

#define EPS_BN 1e-5f

typedef short bf16x8 __attribute__((ext_vector_type(8)));
typedef float f32x4 __attribute__((ext_vector_type(4)));

__device__ __forceinline__ unsigned short f2b(float f)
{
    union { float f; unsigned int u; } c; c.f = f;
    unsigned int u = c.u + 0x7FFFu + ((c.u >> 16) & 1u);
    return (unsigned short)(u >> 16);
}
__device__ __forceinline__ float blo(unsigned int u)
{
    union { unsigned int u; float f; } c; c.u = u << 16; return c.f;
}
__device__ __forceinline__ float bhi(unsigned int u)
{
    union { unsigned int u; float f; } c; c.u = u & 0xFFFF0000u; return c.f;
}

// async global->LDS, 16B per lane; LDS dest = wave-uniform base + lane*16
__device__ __forceinline__ void async_ld16(const unsigned short* g, unsigned short* l)
{
    __builtin_amdgcn_global_load_lds(
        (const __attribute__((address_space(1))) unsigned int*)g,
        (__attribute__((address_space(3))) unsigned int*)l, 16, 0, 0);
}

// relation / type index helpers (branchless compare-sums)
__device__ __forceinline__ int relof_e(int e) {
    return (e>=500000)+(e>=900000)+(e>=1050000)+(e>=1450000)+(e>=1950000)+(e>=2350000);
}
__device__ __forceinline__ int relof_n(int i) {
    return (i>=10000)+(i>=60000)+(i>=63000)+(i>=73000)+(i>=93000)+(i>=113000);
}
__device__ __forceinline__ int eoff_of(int r) {
    return r<1?0 : r<2?500000 : r<3?900000 : r<4?1050000 : r<5?1450000 : r<6?1950000 : 2350000;
}
__device__ __forceinline__ int coff_of(int r) {
    return r<1?0 : r<2?10000 : r<3?60000 : r<4?63000 : r<5?73000 : r<6?93000 : 113000;
}
__device__ __forceinline__ int typ_of(int row) { return (row>=20000)+(row>=70000)+(row>=80000); }
__device__ __forceinline__ int nbound(int t)   { return t<1?20000 : t<2?70000 : t<3?80000 : 83000; }
__device__ __forceinline__ float invR_of(int t){ return t<1?5e-5f : t<2?2e-5f : t<3?1e-4f : (1.0f/3000.0f); }

struct Graph { const int* src[7]; const int* dst[7]; };

__device__ __forceinline__ void relptrs(const Graph& g, int r, const int*& sp, const int*& dp)
{
    sp = g.src[0]; dp = g.dst[0];
    if (r==1){sp=g.src[1];dp=g.dst[1];}
    if (r==2){sp=g.src[2];dp=g.dst[2];}
    if (r==3){sp=g.src[3];dp=g.dst[3];}
    if (r==4){sp=g.src[4];dp=g.dst[4];}
    if (r==5){sp=g.src[5];dp=g.dst[5];}
    if (r==6){sp=g.src[6];dp=g.dst[6];}
}

// ---------------------------------------------------------------- degree histogram (all rels, 1 launch)
__global__ void count_all(Graph g, int* __restrict__ icnt)
{
    for (int e = blockIdx.x * blockDim.x + threadIdx.x; e < 2500000; e += gridDim.x * blockDim.x) {
        int r = relof_e(e);
        const int *sp, *dp; relptrs(g, r, sp, dp);
        int le = e - eoff_of(r);
        atomicAdd(&icnt[coff_of(r) + dp[le]], 1);
    }
}

// ---------------------------------------------------------------- 3-phase global scan
__global__ __launch_bounds__(1024)
void scan1(const int* __restrict__ icnt, int* __restrict__ scanbuf, int* __restrict__ bsums)
{
    __shared__ int lds[1024];
    int tid = threadIdx.x;
    int gid = blockIdx.x * 1024 + tid;
    int v = (gid < 163000) ? icnt[gid] : 0;
    lds[tid] = v;
    __syncthreads();
    for (int d = 1; d < 1024; d <<= 1) {
        int t = (tid >= d) ? lds[tid - d] : 0;
        __syncthreads();
        lds[tid] += t;
        __syncthreads();
    }
    scanbuf[gid] = lds[tid];                  // inclusive within block
    if (tid == 1023) bsums[blockIdx.x] = lds[1023];
}

__global__ __launch_bounds__(256)
void scan2(int* __restrict__ bsums)          // exclusive scan of 160 partials, in place
{
    __shared__ int lds[256];
    int tid = threadIdx.x;
    int v = (tid < 160) ? bsums[tid] : 0;
    lds[tid] = v;
    __syncthreads();
    for (int d = 1; d < 256; d <<= 1) {
        int t = (tid >= d) ? lds[tid - d] : 0;
        __syncthreads();
        lds[tid] += t;
        __syncthreads();
    }
    bsums[tid] = tid ? lds[tid - 1] : 0;
}

// fixup: rowptrG (global cumulative), cur (insert cursors), inv (1/max(deg,1))
__global__ __launch_bounds__(256)
void scan_fix(const int* __restrict__ icnt, const int* __restrict__ scanbuf,
              const int* __restrict__ bsums, int* __restrict__ rowptrG,
              int* __restrict__ cur, float* __restrict__ inv)
{
    int idx = blockIdx.x * blockDim.x + threadIdx.x;
    if (idx > 163000) return;
    int G = bsums[idx >> 10] + ((idx & 1023) ? scanbuf[idx - 1] : 0);
    rowptrG[idx] = G;
    if (idx < 163000) {
        cur[idx] = G;
        inv[idx] = 1.0f / (float)max(icnt[idx], 1);
    }
}

// ---------------------------------------------------------------- CSR fill (all rels, 1 launch)
__global__ void fill_all(Graph g, int* __restrict__ cur, int* __restrict__ csr)
{
    for (int e = blockIdx.x * blockDim.x + threadIdx.x; e < 2500000; e += gridDim.x * blockDim.x) {
        int r = relof_e(e);
        const int *sp, *dp; relptrs(g, r, sp, dp);
        int le = e - eoff_of(r);
        int gidx = coff_of(r) + dp[le];
        csr[atomicAdd(&cur[gidx], 1)] = sp[le];
    }
}

// ---------------------------------------------------------------- f32 -> bf16 bulk convert
__global__ void tob16_kernel(const float* __restrict__ in, unsigned short* __restrict__ out, int n4)
{
    for (int i = blockIdx.x * blockDim.x + threadIdx.x; i < n4; i += gridDim.x * blockDim.x) {
        float4 v = ((const float4*)in)[i];
        uint2 o;
        o.x = (unsigned int)f2b(v.x) | ((unsigned int)f2b(v.y) << 16);
        o.y = (unsigned int)f2b(v.z) | ((unsigned int)f2b(v.w) << 16);
        ((uint2*)out)[i] = o;
    }
}

// ---------------------------------------------------------------- fused gather-mean, all relations in one launch
struct GatherCfg {
    const unsigned short* X[7];
    const int* rowptrG;
    const int* csr;
    const float* inv;
    unsigned short* agg;
};

template <int D>
__global__ __launch_bounds__(256)
void gather_all(GatherCfg c)
{
    constexpr int LPE = D / 8;        // lanes per edge (one uint4 = 16B each)
    constexpr int EPW = 64 / LPE;     // edges per wave-iteration
    int wid = (blockIdx.x * blockDim.x + threadIdx.x) >> 6;
    if (wid >= 163000) return;
    int l = threadIdx.x & 63;
    int q = l & (LPE - 1);
    int gg = l / LPE;
    int r = relof_n(wid);
    const unsigned short* X = c.X[0];
    if (r==1) X=c.X[1];
    if (r==2) X=c.X[2];
    if (r==3) X=c.X[3];
    if (r==4) X=c.X[4];
    if (r==5) X=c.X[5];
    if (r==6) X=c.X[6];
    const unsigned short* Xq = X + q * 8;
    const int* csr = c.csr;
    int beg = c.rowptrG[wid], end = c.rowptrG[wid + 1];
    float acc[8] = {0.f,0.f,0.f,0.f,0.f,0.f,0.f,0.f};
    int it = beg;
    for (; it + 2 * EPW <= end; it += 2 * EPW) {
        int s0 = csr[it + gg];
        int s1 = csr[it + EPW + gg];
        uint4 v0 = *(const uint4*)(Xq + (size_t)s0 * D);
        uint4 v1 = *(const uint4*)(Xq + (size_t)s1 * D);
        acc[0]+=blo(v0.x); acc[1]+=bhi(v0.x); acc[2]+=blo(v0.y); acc[3]+=bhi(v0.y);
        acc[4]+=blo(v0.z); acc[5]+=bhi(v0.z); acc[6]+=blo(v0.w); acc[7]+=bhi(v0.w);
        acc[0]+=blo(v1.x); acc[1]+=bhi(v1.x); acc[2]+=blo(v1.y); acc[3]+=bhi(v1.y);
        acc[4]+=blo(v1.z); acc[5]+=bhi(v1.z); acc[6]+=blo(v1.w); acc[7]+=bhi(v1.w);
    }
    for (; it < end; it += EPW) {
        int i0 = it + gg;
        if (i0 < end) {
            int s0 = csr[i0];
            uint4 v0 = *(const uint4*)(Xq + (size_t)s0 * D);
            acc[0]+=blo(v0.x); acc[1]+=bhi(v0.x); acc[2]+=blo(v0.y); acc[3]+=bhi(v0.y);
            acc[4]+=blo(v0.z); acc[5]+=bhi(v0.z); acc[6]+=blo(v0.w); acc[7]+=bhi(v0.w);
        }
    }
#pragma unroll
    for (int k = 0; k < 8; ++k) {
        if (LPE == 16) acc[k] += __shfl_xor(acc[k], 16);
        acc[k] += __shfl_xor(acc[k], 32);
    }
    if (l < LPE) {
        float inv = c.inv[wid];
        uint4 o;
        o.x = (unsigned int)f2b(acc[0]*inv) | ((unsigned int)f2b(acc[1]*inv) << 16);
        o.y = (unsigned int)f2b(acc[2]*inv) | ((unsigned int)f2b(acc[3]*inv) << 16);
        o.z = (unsigned int)f2b(acc[4]*inv) | ((unsigned int)f2b(acc[5]*inv) << 16);
        o.w = (unsigned int)f2b(acc[6]*inv) | ((unsigned int)f2b(acc[7]*inv) << 16);
        *(uint4*)(c.agg + (size_t)wid * D + q * 8) = o;
    }
}

// ---------------------------------------------------------------- weight prep: sum roots, transpose to [N][K] bf16
// (biases dropped: a per-column constant cancels exactly in train-mode BN's v - mu)
__global__ void wtrans_kernel(const float* __restrict__ Wr, const float* __restrict__ Wl,
                              unsigned short* __restrict__ wsumT, unsigned short* __restrict__ WlT,
                              int K)
{
    const int nrel[4]  = {2, 2, 2, 1};
    const int rl[4][2] = {{4,5},{1,6},{0,3},{2,2}};
    int per = 256 * K;
    int tot = 11 * per;
    for (int idx = blockIdx.x * blockDim.x + threadIdx.x; idx < tot;
         idx += gridDim.x * blockDim.x) {
        if (idx < 4 * per) {
            int t = idx / per, rem = idx - t * per;
            int n = rem / K, k = rem - n * K;
            float s = Wr[(size_t)rl[t][0] * per + k * 256 + n];
            if (nrel[t] > 1) s += Wr[(size_t)rl[t][1] * per + k * 256 + n];
            wsumT[idx] = f2b(s);
        } else {
            int j = idx - 4 * per;
            int r = j / per, rem = j - r * per;
            int n = rem / K, k = rem - n * K;
            WlT[j] = f2b(Wl[(size_t)r * per + k * 256 + n]);
        }
    }
}

// ---------------------------------------------------------------- fused MFMA GEMM, 128x256 tile, 8 waves (2x4),
// global_load_lds staging with pre-swizzled source (rule #21), all 4 types in one launch
struct GemmBatch {
    const unsigned short* A0[4];
    const unsigned short* A1[4];
    const unsigned short* A2[4];
    const unsigned short* B0[4];
    const unsigned short* B1[4];
    const unsigned short* B2[4];
    float* outF;
    unsigned short* outB;
    int R[4]; int bcum[4]; int rowoff[4]; int nsrc[4];
    int K, kshift, outf32;
};

__global__ __launch_bounds__(512, 4)
void gemm_mfma(GemmBatch g)
{
    __shared__ __align__(16) unsigned short Atile[2][128 * 32];   // 16 KB
    __shared__ __align__(16) unsigned short Btile[2][256 * 32];   // 32 KB

    const int tid = threadIdx.x;
    const int bz = blockIdx.x;
    const int t = (bz >= g.bcum[1]) + (bz >= g.bcum[2]) + (bz >= g.bcum[3]);
    const int bm = (bz - g.bcum[t]) << 7;
    const int w = tid >> 6, l = tid & 63;
    const int wr = w >> 2, wc = w & 3;          // 2x4 waves, wave tile 64 rows x 64 cols

    const int R = g.R[t];
    const int K = g.K, kshift = g.kshift, kmask = K - 1;
    const unsigned short* A0t = g.A0[t];
    const unsigned short* A1t = g.A1[t];
    const unsigned short* A2t = g.A2[t];
    const unsigned short* B0t = g.B0[t];
    const unsigned short* B1t = g.B1[t];
    const unsigned short* B2t = g.B2[t];
    const int steps = (g.nsrc[t] * K) >> 5;

    // staging geometry: lane l of wave w fills LDS row (w*16 + (l>>2)), chunk (l&3).
    // LDS[row][c] must hold global[row][c ^ swz(row)], swz(row) = (row>>1)&3 -> pre-swizzle source.
    const int rloc = tid >> 2;                                    // 0..127
    const int swz  = (((tid & 3) ^ ((tid >> 3) & 3)) << 3);       // source k-offset (elems)
    const int srowA = min(bm + rloc, R - 1);                      // clamp: garbage only feeds rows >= R
    const int wseg  = w << 9;                                     // w*512 ushorts = 1KB per wave

    auto stage = [&](int st, int buf) {
        int kglob = st << 5;
        int s  = kglob >> kshift;
        int kk = kglob & kmask;
        const unsigned short* As = (s == 0) ? A0t : (s == 1) ? A1t : A2t;
        const unsigned short* Bs = (s == 0) ? B0t : (s == 1) ? B1t : B2t;
        async_ld16(As + (size_t)srowA * K + kk + swz, &Atile[buf][wseg]);
        async_ld16(Bs + (size_t)rloc  * K + kk + swz, &Btile[buf][wseg]);
        async_ld16(Bs + (size_t)(128 + rloc) * K + kk + swz, &Btile[buf][4096 + wseg]);
    };

    f32x4 acc[4][4];
#pragma unroll
    for (int i = 0; i < 4; ++i)
#pragma unroll
        for (int j = 0; j < 4; ++j)
            acc[i][j] = (f32x4){0.f, 0.f, 0.f, 0.f};

    const int ck = l >> 4;
    const int ra = wr * 64 + (l & 15);
    const int aoff = ra * 32 + ((ck ^ ((ra >> 1) & 3)) << 3);
    const int rb = wc * 64 + (l & 15);
    const int boff = rb * 32 + ((ck ^ ((rb >> 1) & 3)) << 3);   // +16 rows keeps swz invariant

    stage(0, 0);
    __syncthreads();
    int cur = 0;
    for (int st = 0; st < steps; ++st) {
        if (st + 1 < steps) stage(st + 1, cur ^ 1);
        const unsigned short* At = Atile[cur];
        const unsigned short* Bt = Btile[cur];
        bf16x8 af[4], bfr[4];
#pragma unroll
        for (int i = 0; i < 4; ++i) {
            af[i]  = *(const bf16x8*)(At + aoff + i * 512);
            bfr[i] = *(const bf16x8*)(Bt + boff + i * 512);
        }
#pragma unroll
        for (int mi = 0; mi < 4; ++mi)
#pragma unroll
            for (int ni = 0; ni < 4; ++ni)
                acc[mi][ni] = __builtin_amdgcn_mfma_f32_16x16x32_bf16(
                    af[mi], bfr[ni], acc[mi][ni], 0, 0, 0);
        __syncthreads();     // drains next-tile global_load_lds + this tile's ds_reads
        cur ^= 1;
    }

    const int orow0 = bm + wr * 64 + ((l >> 4) << 2);
    const int ocol0 = wc * 64 + (l & 15);
#pragma unroll
    for (int ni = 0; ni < 4; ++ni) {
        int col = ocol0 + ni * 16;
#pragma unroll
        for (int mi = 0; mi < 4; ++mi) {
#pragma unroll
            for (int j = 0; j < 4; ++j) {
                int row = orow0 + mi * 16 + j;
                if (row < R) {
                    float v = acc[mi][ni][j];
                    size_t o = (size_t)(g.rowoff[t] + row) * 256 + col;
                    if (g.outf32) g.outF[o] = v;
                    else          g.outB[o] = f2b(v);
                }
            }
        }
    }
}

// ---------------------------------------------------------------- BatchNorm (train-mode) + ReLU, all types fused
template <int F32>
__global__ __launch_bounds__(256)
void bn_stats_all(const void* __restrict__ Hv, float* __restrict__ stats)
{
    int c = threadIdx.x;
    int r0 = blockIdx.x * 128;
    int r1 = min(r0 + 128, 83000);
    int t = typ_of(r0);
    int nb = nbound(t);
    float s = 0.f, ss = 0.f;
    for (int r = r0; r < r1; ++r) {
        if (r == nb) {
            atomicAdd(&stats[t * 512 + c], s);
            atomicAdd(&stats[t * 512 + 256 + c], ss);
            s = ss = 0.f; ++t; nb = nbound(t);
        }
        float v;
        if (F32) v = ((const float*)Hv)[(size_t)r * 256 + c];
        else { unsigned int u = ((const unsigned short*)Hv)[(size_t)r * 256 + c]; v = blo(u); }
        s += v; ss += v * v;
    }
    atomicAdd(&stats[t * 512 + c], s);
    atomicAdd(&stats[t * 512 + 256 + c], ss);
}

template <int F32>
__global__ __launch_bounds__(256)
void bn_apply_all(void* __restrict__ Hv, const float* __restrict__ stats,
                  const float* __restrict__ gg, const float* __restrict__ be)
{
    const int total4 = 83000 * 64;
    for (int i4 = blockIdx.x * blockDim.x + threadIdx.x; i4 < total4;
         i4 += gridDim.x * blockDim.x) {
        int row = i4 >> 6;
        int c4  = (i4 & 63) << 2;
        int t   = typ_of(row);
        float invR = invR_of(t);
        const float* st = stats + t * 512;
        float vin[4];
        if (F32) {
            float4 v = *(const float4*)((const float*)Hv + (size_t)row * 256 + c4);
            vin[0]=v.x; vin[1]=v.y; vin[2]=v.z; vin[3]=v.w;
        } else {
            uint2 u = *(const uint2*)((const unsigned short*)Hv + (size_t)row * 256 + c4);
            vin[0]=blo(u.x); vin[1]=bhi(u.x); vin[2]=blo(u.y); vin[3]=bhi(u.y);
        }
        float vout[4];
#pragma unroll
        for (int k = 0; k < 4; ++k) {
            int c = c4 + k;
            float mu  = st[c] * invR;
            float var = st[256 + c] * invR - mu * mu;
            float sc  = rsqrtf(var + EPS_BN) * gg[c];
            float v   = (vin[k] - mu) * sc + be[c];
            vout[k] = fmaxf(v, 0.f);
        }
        if (F32) {
            float4 o; o.x=vout[0]; o.y=vout[1]; o.z=vout[2]; o.w=vout[3];
            *(float4*)((float*)Hv + (size_t)row * 256 + c4) = o;
        } else {
            uint2 o;
            o.x = (unsigned int)f2b(vout[0]) | ((unsigned int)f2b(vout[1]) << 16);
            o.y = (unsigned int)f2b(vout[2]) | ((unsigned int)f2b(vout[3]) << 16);
            *(uint2*)((unsigned short*)Hv + (size_t)row * 256 + c4) = o;
        }
    }
}

// ---------------------------------------------------------------- host
extern "C" void kernel_launch(void* const* d_in, const int* in_sizes, int n_in,
                              void* d_out, int out_size, void* d_ws, size_t ws_size,
                              hipStream_t stream)
{
    static const int Nn[4]   = {20000, 50000, 10000, 3000};
    static const int roff[4] = {0, 20000, 70000, 80000};
    static const int rst[7]  = {0, 0, 1, 1, 2, 1, 3};
    static const int coff[7] = {0, 10000, 60000, 63000, 73000, 93000, 113000};
    static const int trels[4][2] = {{4,5},{1,6},{0,3},{2,2}};
    static const int tnrel[4]    = {2, 2, 2, 1};
    const int CNT_TOTAL = 163000;

    const float* x[4];
    for (int t = 0; t < 4; ++t) x[t] = (const float*)d_in[t];
    Graph graph;
    for (int i = 0; i < 7; ++i) {
        graph.src[i] = (const int*)d_in[4 + 2 * i];
        graph.dst[i] = (const int*)d_in[5 + 2 * i];
    }
    const float* W1l = (const float*)d_in[18];
    const float* W1r = (const float*)d_in[19];
    const float* W2l = (const float*)d_in[21];
    const float* W2r = (const float*)d_in[22];
    const float* g1  = (const float*)d_in[24];
    const float* be1 = (const float*)d_in[25];
    const float* g2  = (const float*)d_in[26];
    const float* be2 = (const float*)d_in[27];
    float* out = (float*)d_out;
    (void)n_in; (void)in_sizes; (void)out_size; (void)ws_size;

    // ---- workspace carve (~141 MB)
    char* w = (char*)d_ws;
    size_t off = 0;
    auto carve = [&](size_t bytes) -> void* {
        void* p = (void*)(w + off);
        off = (off + bytes + 255) & ~(size_t)255;
        return p;
    };
    int*   icnt    = (int*)carve((size_t)CNT_TOTAL * 4);
    int*   cur     = (int*)carve((size_t)CNT_TOTAL * 4);
    int*   rowptrG = (int*)carve((size_t)(CNT_TOTAL + 1) * 4);
    int*   csr     = (int*)carve((size_t)2500000 * 4);
    int*   scanbuf = (int*)carve((size_t)163840 * 4);
    int*   bsums   = (int*)carve((size_t)256 * 4);
    float* inv     = (float*)carve((size_t)CNT_TOTAL * 4);
    float* stats   = (float*)carve((size_t)4 * 512 * 4);
    unsigned short* wsumT = (unsigned short*)carve((size_t)4 * 256 * 256 * 2);
    unsigned short* WlT   = (unsigned short*)carve((size_t)7 * 256 * 256 * 2);
    unsigned short* U     = (unsigned short*)carve((size_t)163000 * 256 * 2); // union region
    unsigned short* hb    = (unsigned short*)carve((size_t)83000 * 256 * 2);
    unsigned short* xb    = U;                        // layer-1: bf16 inputs (21.25 MB)
    unsigned short* aggL1 = U + (size_t)83000 * 128;  // layer-1 agg (after xb)
    unsigned short* aggL2 = U;                        // layer-2 agg (xb dead by then)

    // ---- CSR build (globally-cumulative rowptr; shared by both layers)
    hipMemsetAsync(icnt, 0, (size_t)CNT_TOTAL * 4, stream);
    count_all<<<2048, 256, 0, stream>>>(graph, icnt);
    scan1<<<160, 1024, 0, stream>>>(icnt, scanbuf, bsums);
    scan2<<<1, 256, 0, stream>>>(bsums);
    scan_fix<<<(CNT_TOTAL + 256) / 256, 256, 0, stream>>>(icnt, scanbuf, bsums,
                                                          rowptrG, cur, inv);
    fill_all<<<2048, 256, 0, stream>>>(graph, cur, csr);

    // ---- x -> bf16
    for (int t = 0; t < 4; ++t)
        tob16_kernel<<<512, 256, 0, stream>>>(x[t], xb + (size_t)roff[t] * 128, Nn[t] * 32);

    for (int layer = 0; layer < 2; ++layer) {
        const int K = layer ? 256 : 128;
        const float* Wl = layer ? W2l : W1l;
        const float* Wr = layer ? W2r : W1r;
        const float* gg = layer ? g2  : g1;
        const float* be = layer ? be2 : be1;
        unsigned short* agg = layer ? aggL2 : aggL1;

        wtrans_kernel<<<1024, 256, 0, stream>>>(Wr, Wl, wsumT, WlT, K);

        GatherCfg gc;
        for (int r = 0; r < 7; ++r)
            gc.X[r] = layer ? (hb + (size_t)roff[rst[r]] * 256)
                            : (xb + (size_t)roff[rst[r]] * 128);
        gc.rowptrG = rowptrG; gc.csr = csr; gc.inv = inv; gc.agg = agg;
        if (layer == 0) gather_all<128><<<40750, 256, 0, stream>>>(gc);
        else            gather_all<256><<<40750, 256, 0, stream>>>(gc);

        GemmBatch gb;
        for (int t = 0; t < 4; ++t) {
            gb.A0[t] = layer ? (hb + (size_t)roff[t] * 256) : (xb + (size_t)roff[t] * 128);
            gb.A1[t] = agg + (size_t)coff[trels[t][0]] * K;
            gb.A2[t] = (tnrel[t] > 1) ? (agg + (size_t)coff[trels[t][1]] * K) : gb.A1[t];
            gb.B0[t] = wsumT + (size_t)t * 256 * K;
            gb.B1[t] = WlT + (size_t)trels[t][0] * 256 * K;
            gb.B2[t] = (tnrel[t] > 1) ? (WlT + (size_t)trels[t][1] * 256 * K) : gb.B1[t];
            gb.R[t] = Nn[t];
            gb.rowoff[t] = roff[t];
            gb.nsrc[t] = 1 + tnrel[t];
        }
        gb.bcum[0] = 0; gb.bcum[1] = 157; gb.bcum[2] = 548; gb.bcum[3] = 627;
        gb.outF = out; gb.outB = hb;
        gb.K = K; gb.kshift = layer ? 8 : 7; gb.outf32 = layer;
        gemm_mfma<<<651, 512, 0, stream>>>(gb);

        hipMemsetAsync(stats, 0, (size_t)4 * 512 * 4, stream);
        if (layer == 0) {
            bn_stats_all<0><<<649, 256, 0, stream>>>(hb, stats);
            bn_apply_all<0><<<2048, 256, 0, stream>>>(hb, stats, gg, be);
        } else {
            bn_stats_all<1><<<649, 256, 0, stream>>>(out, stats);
            bn_apply_all<1><<<2048, 256, 0, stream>>>(out, stats, gg, be);
        }
    }
}

// Round 7
// 864.101 us; speedup vs baseline: 5.5695x; 1.0701x over previous
//
#include <hip/hip_runtime.h>

#define EPS_BN 1e-5f

typedef short bf16x8 __attribute__((ext_vector_type(8)));
typedef float f32x4 __attribute__((ext_vector_type(4)));

__device__ __forceinline__ unsigned short f2b(float f)
{
    union { float f; unsigned int u; } c; c.f = f;
    unsigned int u = c.u + 0x7FFFu + ((c.u >> 16) & 1u);
    return (unsigned short)(u >> 16);
}
__device__ __forceinline__ float blo(unsigned int u)
{
    union { unsigned int u; float f; } c; c.u = u << 16; return c.f;
}
__device__ __forceinline__ float bhi(unsigned int u)
{
    union { unsigned int u; float f; } c; c.u = u & 0xFFFF0000u; return c.f;
}

// async global->LDS, 16B per lane; LDS dest = wave-uniform base + lane*16
__device__ __forceinline__ void async_ld16(const unsigned short* g, unsigned short* l)
{
    __builtin_amdgcn_global_load_lds(
        (const __attribute__((address_space(1))) unsigned int*)g,
        (__attribute__((address_space(3))) unsigned int*)l, 16, 0, 0);
}

// relation / type index helpers (branchless compare-sums)
__device__ __forceinline__ int relof_e(int e) {
    return (e>=500000)+(e>=900000)+(e>=1050000)+(e>=1450000)+(e>=1950000)+(e>=2350000);
}
__device__ __forceinline__ int relof_n(int i) {
    return (i>=10000)+(i>=60000)+(i>=63000)+(i>=73000)+(i>=93000)+(i>=113000);
}
__device__ __forceinline__ int eoff_of(int r) {
    return r<1?0 : r<2?500000 : r<3?900000 : r<4?1050000 : r<5?1450000 : r<6?1950000 : 2350000;
}
__device__ __forceinline__ int coff_of(int r) {
    return r<1?0 : r<2?10000 : r<3?60000 : r<4?63000 : r<5?73000 : r<6?93000 : 113000;
}
__device__ __forceinline__ int typ_of(int row) { return (row>=20000)+(row>=70000)+(row>=80000); }
__device__ __forceinline__ int nbound(int t)   { return t<1?20000 : t<2?70000 : t<3?80000 : 83000; }
__device__ __forceinline__ float invR_of(int t){ return t<1?5e-5f : t<2?2e-5f : t<3?1e-4f : (1.0f/3000.0f); }

struct Graph { const int* src[7]; const int* dst[7]; };

__device__ __forceinline__ void relptrs(const Graph& g, int r, const int*& sp, const int*& dp)
{
    sp = g.src[0]; dp = g.dst[0];
    if (r==1){sp=g.src[1];dp=g.dst[1];}
    if (r==2){sp=g.src[2];dp=g.dst[2];}
    if (r==3){sp=g.src[3];dp=g.dst[3];}
    if (r==4){sp=g.src[4];dp=g.dst[4];}
    if (r==5){sp=g.src[5];dp=g.dst[5];}
    if (r==6){sp=g.src[6];dp=g.dst[6];}
}

// ---------------------------------------------------------------- degree histogram (all rels, 1 launch)
__global__ void count_all(Graph g, int* __restrict__ icnt)
{
    for (int e = blockIdx.x * blockDim.x + threadIdx.x; e < 2500000; e += gridDim.x * blockDim.x) {
        int r = relof_e(e);
        const int *sp, *dp; relptrs(g, r, sp, dp);
        int le = e - eoff_of(r);
        atomicAdd(&icnt[coff_of(r) + dp[le]], 1);
    }
}

// ---------------------------------------------------------------- 3-phase global scan
__global__ __launch_bounds__(1024)
void scan1(const int* __restrict__ icnt, int* __restrict__ scanbuf, int* __restrict__ bsums)
{
    __shared__ int lds[1024];
    int tid = threadIdx.x;
    int gid = blockIdx.x * 1024 + tid;
    int v = (gid < 163000) ? icnt[gid] : 0;
    lds[tid] = v;
    __syncthreads();
    for (int d = 1; d < 1024; d <<= 1) {
        int t = (tid >= d) ? lds[tid - d] : 0;
        __syncthreads();
        lds[tid] += t;
        __syncthreads();
    }
    scanbuf[gid] = lds[tid];                  // inclusive within block
    if (tid == 1023) bsums[blockIdx.x] = lds[1023];
}

__global__ __launch_bounds__(256)
void scan2(int* __restrict__ bsums)          // exclusive scan of 160 partials, in place
{
    __shared__ int lds[256];
    int tid = threadIdx.x;
    int v = (tid < 160) ? bsums[tid] : 0;
    lds[tid] = v;
    __syncthreads();
    for (int d = 1; d < 256; d <<= 1) {
        int t = (tid >= d) ? lds[tid - d] : 0;
        __syncthreads();
        lds[tid] += t;
        __syncthreads();
    }
    bsums[tid] = tid ? lds[tid - 1] : 0;
}

// fixup: rowptrG (global cumulative), cur (insert cursors), inv (1/max(deg,1)),
// sliceid: 8-way partition of dst space with EQUAL EDGE COUNT per slice (for fill locality)
__global__ __launch_bounds__(256)
void scan_fix(const int* __restrict__ icnt, const int* __restrict__ scanbuf,
              const int* __restrict__ bsums, int* __restrict__ rowptrG,
              int* __restrict__ cur, float* __restrict__ inv,
              unsigned char* __restrict__ sliceid)
{
    int idx = blockIdx.x * blockDim.x + threadIdx.x;
    if (idx > 163000) return;
    int G = bsums[idx >> 10] + ((idx & 1023) ? scanbuf[idx - 1] : 0);
    rowptrG[idx] = G;
    if (idx < 163000) {
        cur[idx] = G;
        inv[idx] = 1.0f / (float)max(icnt[idx], 1);
        int s = G / 312500;                    // 2.5M edges / 8 slices
        sliceid[idx] = (unsigned char)(s > 7 ? 7 : s);
    }
}

// ---------------------------------------------------------------- CSR fill, XCD-sliced
// block b handles slice (b&7); default round-robin dispatch keeps a slice on one XCD,
// so cursor atomics + csr writes stay in one L2 and lines fill densely (heuristic only —
// correctness holds for any block->XCD mapping since slices partition the dst space).
__global__ void fill_all(Graph g, const unsigned char* __restrict__ sliceid,
                         int* __restrict__ cur, int* __restrict__ csr)
{
    const int slice = blockIdx.x & 7;
    const int bper  = gridDim.x >> 3;
    const int bidx  = blockIdx.x >> 3;
    for (int e = bidx * blockDim.x + threadIdx.x; e < 2500000; e += bper * blockDim.x) {
        int r = relof_e(e);
        const int *sp, *dp; relptrs(g, r, sp, dp);
        int le = e - eoff_of(r);
        int gidx = coff_of(r) + dp[le];
        if (sliceid[gidx] == slice)
            csr[atomicAdd(&cur[gidx], 1)] = sp[le];
    }
}

// ---------------------------------------------------------------- f32 -> bf16 bulk convert
__global__ void tob16_kernel(const float* __restrict__ in, unsigned short* __restrict__ out, int n4)
{
    for (int i = blockIdx.x * blockDim.x + threadIdx.x; i < n4; i += gridDim.x * blockDim.x) {
        float4 v = ((const float4*)in)[i];
        uint2 o;
        o.x = (unsigned int)f2b(v.x) | ((unsigned int)f2b(v.y) << 16);
        o.y = (unsigned int)f2b(v.z) | ((unsigned int)f2b(v.w) << 16);
        ((uint2*)out)[i] = o;
    }
}

// ---------------------------------------------------------------- fused gather-mean, all relations in one launch
struct GatherCfg {
    const unsigned short* X[7];
    const int* rowptrG;
    const int* csr;
    const float* inv;
    unsigned short* agg;
};

template <int D>
__global__ __launch_bounds__(256)
void gather_all(GatherCfg c)
{
    constexpr int LPE = D / 8;        // lanes per edge (one uint4 = 16B each)
    constexpr int EPW = 64 / LPE;     // edges per wave-iteration
    int wid = (blockIdx.x * blockDim.x + threadIdx.x) >> 6;
    if (wid >= 163000) return;
    int l = threadIdx.x & 63;
    int q = l & (LPE - 1);
    int gg = l / LPE;
    int r = relof_n(wid);
    const unsigned short* X = c.X[0];
    if (r==1) X=c.X[1];
    if (r==2) X=c.X[2];
    if (r==3) X=c.X[3];
    if (r==4) X=c.X[4];
    if (r==5) X=c.X[5];
    if (r==6) X=c.X[6];
    const unsigned short* Xq = X + q * 8;
    const int* csr = c.csr;
    int beg = c.rowptrG[wid], end = c.rowptrG[wid + 1];
    float acc[8] = {0.f,0.f,0.f,0.f,0.f,0.f,0.f,0.f};
    int it = beg;
    // 4 edges in flight per lane-group (latency hiding)
    for (; it + 4 * EPW <= end; it += 4 * EPW) {
        int s0 = csr[it + gg];
        int s1 = csr[it + EPW + gg];
        int s2 = csr[it + 2 * EPW + gg];
        int s3 = csr[it + 3 * EPW + gg];
        uint4 v0 = *(const uint4*)(Xq + (size_t)s0 * D);
        uint4 v1 = *(const uint4*)(Xq + (size_t)s1 * D);
        uint4 v2 = *(const uint4*)(Xq + (size_t)s2 * D);
        uint4 v3 = *(const uint4*)(Xq + (size_t)s3 * D);
        acc[0]+=blo(v0.x); acc[1]+=bhi(v0.x); acc[2]+=blo(v0.y); acc[3]+=bhi(v0.y);
        acc[4]+=blo(v0.z); acc[5]+=bhi(v0.z); acc[6]+=blo(v0.w); acc[7]+=bhi(v0.w);
        acc[0]+=blo(v1.x); acc[1]+=bhi(v1.x); acc[2]+=blo(v1.y); acc[3]+=bhi(v1.y);
        acc[4]+=blo(v1.z); acc[5]+=bhi(v1.z); acc[6]+=blo(v1.w); acc[7]+=bhi(v1.w);
        acc[0]+=blo(v2.x); acc[1]+=bhi(v2.x); acc[2]+=blo(v2.y); acc[3]+=bhi(v2.y);
        acc[4]+=blo(v2.z); acc[5]+=bhi(v2.z); acc[6]+=blo(v2.w); acc[7]+=bhi(v2.w);
        acc[0]+=blo(v3.x); acc[1]+=bhi(v3.x); acc[2]+=blo(v3.y); acc[3]+=bhi(v3.y);
        acc[4]+=blo(v3.z); acc[5]+=bhi(v3.z); acc[6]+=blo(v3.w); acc[7]+=bhi(v3.w);
    }
    for (; it < end; it += EPW) {
        int i0 = it + gg;
        if (i0 < end) {
            int s0 = csr[i0];
            uint4 v0 = *(const uint4*)(Xq + (size_t)s0 * D);
            acc[0]+=blo(v0.x); acc[1]+=bhi(v0.x); acc[2]+=blo(v0.y); acc[3]+=bhi(v0.y);
            acc[4]+=blo(v0.z); acc[5]+=bhi(v0.z); acc[6]+=blo(v0.w); acc[7]+=bhi(v0.w);
        }
    }
#pragma unroll
    for (int k = 0; k < 8; ++k) {
        if (LPE == 16) acc[k] += __shfl_xor(acc[k], 16);
        acc[k] += __shfl_xor(acc[k], 32);
    }
    if (l < LPE) {
        float inv = c.inv[wid];
        uint4 o;
        o.x = (unsigned int)f2b(acc[0]*inv) | ((unsigned int)f2b(acc[1]*inv) << 16);
        o.y = (unsigned int)f2b(acc[2]*inv) | ((unsigned int)f2b(acc[3]*inv) << 16);
        o.z = (unsigned int)f2b(acc[4]*inv) | ((unsigned int)f2b(acc[5]*inv) << 16);
        o.w = (unsigned int)f2b(acc[6]*inv) | ((unsigned int)f2b(acc[7]*inv) << 16);
        *(uint4*)(c.agg + (size_t)wid * D + q * 8) = o;
    }
}

// ---------------------------------------------------------------- weight prep: sum roots, transpose to [N][K] bf16
// (biases dropped: a per-column constant cancels exactly in train-mode BN's v - mu)
__global__ void wtrans_kernel(const float* __restrict__ Wr, const float* __restrict__ Wl,
                              unsigned short* __restrict__ wsumT, unsigned short* __restrict__ WlT,
                              int K)
{
    const int nrel[4]  = {2, 2, 2, 1};
    const int rl[4][2] = {{4,5},{1,6},{0,3},{2,2}};
    int per = 256 * K;
    int tot = 11 * per;
    for (int idx = blockIdx.x * blockDim.x + threadIdx.x; idx < tot;
         idx += gridDim.x * blockDim.x) {
        if (idx < 4 * per) {
            int t = idx / per, rem = idx - t * per;
            int n = rem / K, k = rem - n * K;
            float s = Wr[(size_t)rl[t][0] * per + k * 256 + n];
            if (nrel[t] > 1) s += Wr[(size_t)rl[t][1] * per + k * 256 + n];
            wsumT[idx] = f2b(s);
        } else {
            int j = idx - 4 * per;
            int r = j / per, rem = j - r * per;
            int n = rem / K, k = rem - n * K;
            WlT[j] = f2b(Wl[(size_t)r * per + k * 256 + n]);
        }
    }
}

// ---------------------------------------------------------------- fused MFMA GEMM, 128x256 tile, 8 waves (2x4),
// global_load_lds staging with pre-swizzled source (rule #21), all 4 types in one launch
struct GemmBatch {
    const unsigned short* A0[4];
    const unsigned short* A1[4];
    const unsigned short* A2[4];
    const unsigned short* B0[4];
    const unsigned short* B1[4];
    const unsigned short* B2[4];
    float* outF;
    unsigned short* outB;
    int R[4]; int bcum[4]; int rowoff[4]; int nsrc[4];
    int K, kshift, outf32;
};

__global__ __launch_bounds__(512, 4)
void gemm_mfma(GemmBatch g)
{
    __shared__ __align__(16) unsigned short Atile[2][128 * 32];   // 16 KB
    __shared__ __align__(16) unsigned short Btile[2][256 * 32];   // 32 KB

    const int tid = threadIdx.x;
    const int bz = blockIdx.x;
    const int t = (bz >= g.bcum[1]) + (bz >= g.bcum[2]) + (bz >= g.bcum[3]);
    const int bm = (bz - g.bcum[t]) << 7;
    const int w = tid >> 6, l = tid & 63;
    const int wr = w >> 2, wc = w & 3;          // 2x4 waves, wave tile 64 rows x 64 cols

    const int R = g.R[t];
    const int K = g.K, kshift = g.kshift, kmask = K - 1;
    const unsigned short* A0t = g.A0[t];
    const unsigned short* A1t = g.A1[t];
    const unsigned short* A2t = g.A2[t];
    const unsigned short* B0t = g.B0[t];
    const unsigned short* B1t = g.B1[t];
    const unsigned short* B2t = g.B2[t];
    const int steps = (g.nsrc[t] * K) >> 5;

    // staging geometry: lane l of wave w fills LDS row (w*16 + (l>>2)), chunk (l&3).
    // LDS[row][c] must hold global[row][c ^ swz(row)], swz(row) = (row>>1)&3 -> pre-swizzle source.
    const int rloc = tid >> 2;                                    // 0..127
    const int swz  = (((tid & 3) ^ ((tid >> 3) & 3)) << 3);       // source k-offset (elems)
    const int srowA = min(bm + rloc, R - 1);                      // clamp: garbage only feeds rows >= R
    const int wseg  = w << 9;                                     // w*512 ushorts = 1KB per wave

    auto stage = [&](int st, int buf) {
        int kglob = st << 5;
        int s  = kglob >> kshift;
        int kk = kglob & kmask;
        const unsigned short* As = (s == 0) ? A0t : (s == 1) ? A1t : A2t;
        const unsigned short* Bs = (s == 0) ? B0t : (s == 1) ? B1t : B2t;
        async_ld16(As + (size_t)srowA * K + kk + swz, &Atile[buf][wseg]);
        async_ld16(Bs + (size_t)rloc  * K + kk + swz, &Btile[buf][wseg]);
        async_ld16(Bs + (size_t)(128 + rloc) * K + kk + swz, &Btile[buf][4096 + wseg]);
    };

    f32x4 acc[4][4];
#pragma unroll
    for (int i = 0; i < 4; ++i)
#pragma unroll
        for (int j = 0; j < 4; ++j)
            acc[i][j] = (f32x4){0.f, 0.f, 0.f, 0.f};

    const int ck = l >> 4;
    const int ra = wr * 64 + (l & 15);
    const int aoff = ra * 32 + ((ck ^ ((ra >> 1) & 3)) << 3);
    const int rb = wc * 64 + (l & 15);
    const int boff = rb * 32 + ((ck ^ ((rb >> 1) & 3)) << 3);   // +16 rows keeps swz invariant

    stage(0, 0);
    __syncthreads();
    int cur = 0;
    for (int st = 0; st < steps; ++st) {
        if (st + 1 < steps) stage(st + 1, cur ^ 1);
        const unsigned short* At = Atile[cur];
        const unsigned short* Bt = Btile[cur];
        bf16x8 af[4], bfr[4];
#pragma unroll
        for (int i = 0; i < 4; ++i) {
            af[i]  = *(const bf16x8*)(At + aoff + i * 512);
            bfr[i] = *(const bf16x8*)(Bt + boff + i * 512);
        }
#pragma unroll
        for (int mi = 0; mi < 4; ++mi)
#pragma unroll
            for (int ni = 0; ni < 4; ++ni)
                acc[mi][ni] = __builtin_amdgcn_mfma_f32_16x16x32_bf16(
                    af[mi], bfr[ni], acc[mi][ni], 0, 0, 0);
        __syncthreads();     // drains next-tile global_load_lds + this tile's ds_reads
        cur ^= 1;
    }

    const int orow0 = bm + wr * 64 + ((l >> 4) << 2);
    const int ocol0 = wc * 64 + (l & 15);
#pragma unroll
    for (int ni = 0; ni < 4; ++ni) {
        int col = ocol0 + ni * 16;
#pragma unroll
        for (int mi = 0; mi < 4; ++mi) {
#pragma unroll
            for (int j = 0; j < 4; ++j) {
                int row = orow0 + mi * 16 + j;
                if (row < R) {
                    float v = acc[mi][ni][j];
                    size_t o = (size_t)(g.rowoff[t] + row) * 256 + col;
                    if (g.outf32) g.outF[o] = v;
                    else          g.outB[o] = f2b(v);
                }
            }
        }
    }
}

// ---------------------------------------------------------------- BatchNorm (train-mode) + ReLU, all types fused
template <int F32>
__global__ __launch_bounds__(256)
void bn_stats_all(const void* __restrict__ Hv, float* __restrict__ stats)
{
    int c = threadIdx.x;
    int r0 = blockIdx.x * 128;
    int r1 = min(r0 + 128, 83000);
    int t = typ_of(r0);
    int nb = nbound(t);
    float s = 0.f, ss = 0.f;
    for (int r = r0; r < r1; ++r) {
        if (r == nb) {
            atomicAdd(&stats[t * 512 + c], s);
            atomicAdd(&stats[t * 512 + 256 + c], ss);
            s = ss = 0.f; ++t; nb = nbound(t);
        }
        float v;
        if (F32) v = ((const float*)Hv)[(size_t)r * 256 + c];
        else { unsigned int u = ((const unsigned short*)Hv)[(size_t)r * 256 + c]; v = blo(u); }
        s += v; ss += v * v;
    }
    atomicAdd(&stats[t * 512 + c], s);
    atomicAdd(&stats[t * 512 + 256 + c], ss);
}

template <int F32>
__global__ __launch_bounds__(256)
void bn_apply_all(void* __restrict__ Hv, const float* __restrict__ stats,
                  const float* __restrict__ gg, const float* __restrict__ be)
{
    const int total4 = 83000 * 64;
    for (int i4 = blockIdx.x * blockDim.x + threadIdx.x; i4 < total4;
         i4 += gridDim.x * blockDim.x) {
        int row = i4 >> 6;
        int c4  = (i4 & 63) << 2;
        int t   = typ_of(row);
        float invR = invR_of(t);
        const float* st = stats + t * 512;
        float vin[4];
        if (F32) {
            float4 v = *(const float4*)((const float*)Hv + (size_t)row * 256 + c4);
            vin[0]=v.x; vin[1]=v.y; vin[2]=v.z; vin[3]=v.w;
        } else {
            uint2 u = *(const uint2*)((const unsigned short*)Hv + (size_t)row * 256 + c4);
            vin[0]=blo(u.x); vin[1]=bhi(u.x); vin[2]=blo(u.y); vin[3]=bhi(u.y);
        }
        float vout[4];
#pragma unroll
        for (int k = 0; k < 4; ++k) {
            int c = c4 + k;
            float mu  = st[c] * invR;
            float var = st[256 + c] * invR - mu * mu;
            float sc  = rsqrtf(var + EPS_BN) * gg[c];
            float v   = (vin[k] - mu) * sc + be[c];
            vout[k] = fmaxf(v, 0.f);
        }
        if (F32) {
            float4 o; o.x=vout[0]; o.y=vout[1]; o.z=vout[2]; o.w=vout[3];
            *(float4*)((float*)Hv + (size_t)row * 256 + c4) = o;
        } else {
            uint2 o;
            o.x = (unsigned int)f2b(vout[0]) | ((unsigned int)f2b(vout[1]) << 16);
            o.y = (unsigned int)f2b(vout[2]) | ((unsigned int)f2b(vout[3]) << 16);
            *(uint2*)((unsigned short*)Hv + (size_t)row * 256 + c4) = o;
        }
    }
}

// ---------------------------------------------------------------- host
extern "C" void kernel_launch(void* const* d_in, const int* in_sizes, int n_in,
                              void* d_out, int out_size, void* d_ws, size_t ws_size,
                              hipStream_t stream)
{
    static const int Nn[4]   = {20000, 50000, 10000, 3000};
    static const int roff[4] = {0, 20000, 70000, 80000};
    static const int rst[7]  = {0, 0, 1, 1, 2, 1, 3};
    static const int coff[7] = {0, 10000, 60000, 63000, 73000, 93000, 113000};
    static const int trels[4][2] = {{4,5},{1,6},{0,3},{2,2}};
    static const int tnrel[4]    = {2, 2, 2, 1};
    const int CNT_TOTAL = 163000;

    const float* x[4];
    for (int t = 0; t < 4; ++t) x[t] = (const float*)d_in[t];
    Graph graph;
    for (int i = 0; i < 7; ++i) {
        graph.src[i] = (const int*)d_in[4 + 2 * i];
        graph.dst[i] = (const int*)d_in[5 + 2 * i];
    }
    const float* W1l = (const float*)d_in[18];
    const float* W1r = (const float*)d_in[19];
    const float* W2l = (const float*)d_in[21];
    const float* W2r = (const float*)d_in[22];
    const float* g1  = (const float*)d_in[24];
    const float* be1 = (const float*)d_in[25];
    const float* g2  = (const float*)d_in[26];
    const float* be2 = (const float*)d_in[27];
    float* out = (float*)d_out;
    (void)n_in; (void)in_sizes; (void)out_size; (void)ws_size;

    // ---- workspace carve (~141 MB)
    char* w = (char*)d_ws;
    size_t off = 0;
    auto carve = [&](size_t bytes) -> void* {
        void* p = (void*)(w + off);
        off = (off + bytes + 255) & ~(size_t)255;
        return p;
    };
    int*   icnt    = (int*)carve((size_t)CNT_TOTAL * 4);
    int*   cur     = (int*)carve((size_t)CNT_TOTAL * 4);
    int*   rowptrG = (int*)carve((size_t)(CNT_TOTAL + 1) * 4);
    int*   csr     = (int*)carve((size_t)2500000 * 4);
    int*   scanbuf = (int*)carve((size_t)163840 * 4);
    int*   bsums   = (int*)carve((size_t)256 * 4);
    float* inv     = (float*)carve((size_t)CNT_TOTAL * 4);
    float* stats   = (float*)carve((size_t)4 * 512 * 4);
    unsigned char* sliceid = (unsigned char*)carve((size_t)CNT_TOTAL);
    unsigned short* wsumT = (unsigned short*)carve((size_t)4 * 256 * 256 * 2);
    unsigned short* WlT   = (unsigned short*)carve((size_t)7 * 256 * 256 * 2);
    unsigned short* U     = (unsigned short*)carve((size_t)163000 * 256 * 2); // union region
    unsigned short* hb    = (unsigned short*)carve((size_t)83000 * 256 * 2);
    unsigned short* xb    = U;                        // layer-1: bf16 inputs (21.25 MB)
    unsigned short* aggL1 = U + (size_t)83000 * 128;  // layer-1 agg (after xb)
    unsigned short* aggL2 = U;                        // layer-2 agg (xb dead by then)

    // ---- CSR build (globally-cumulative rowptr; shared by both layers)
    hipMemsetAsync(icnt, 0, (size_t)CNT_TOTAL * 4, stream);
    count_all<<<2048, 256, 0, stream>>>(graph, icnt);
    scan1<<<160, 1024, 0, stream>>>(icnt, scanbuf, bsums);
    scan2<<<1, 256, 0, stream>>>(bsums);
    scan_fix<<<(CNT_TOTAL + 256) / 256, 256, 0, stream>>>(icnt, scanbuf, bsums,
                                                          rowptrG, cur, inv, sliceid);
    fill_all<<<2048, 256, 0, stream>>>(graph, sliceid, cur, csr);

    // ---- x -> bf16
    for (int t = 0; t < 4; ++t)
        tob16_kernel<<<512, 256, 0, stream>>>(x[t], xb + (size_t)roff[t] * 128, Nn[t] * 32);

    for (int layer = 0; layer < 2; ++layer) {
        const int K = layer ? 256 : 128;
        const float* Wl = layer ? W2l : W1l;
        const float* Wr = layer ? W2r : W1r;
        const float* gg = layer ? g2  : g1;
        const float* be = layer ? be2 : be1;
        unsigned short* agg = layer ? aggL2 : aggL1;

        wtrans_kernel<<<1024, 256, 0, stream>>>(Wr, Wl, wsumT, WlT, K);

        GatherCfg gc;
        for (int r = 0; r < 7; ++r)
            gc.X[r] = layer ? (hb + (size_t)roff[rst[r]] * 256)
                            : (xb + (size_t)roff[rst[r]] * 128);
        gc.rowptrG = rowptrG; gc.csr = csr; gc.inv = inv; gc.agg = agg;
        if (layer == 0) gather_all<128><<<40750, 256, 0, stream>>>(gc);
        else            gather_all<256><<<40750, 256, 0, stream>>>(gc);

        GemmBatch gb;
        for (int t = 0; t < 4; ++t) {
            gb.A0[t] = layer ? (hb + (size_t)roff[t] * 256) : (xb + (size_t)roff[t] * 128);
            gb.A1[t] = agg + (size_t)coff[trels[t][0]] * K;
            gb.A2[t] = (tnrel[t] > 1) ? (agg + (size_t)coff[trels[t][1]] * K) : gb.A1[t];
            gb.B0[t] = wsumT + (size_t)t * 256 * K;
            gb.B1[t] = WlT + (size_t)trels[t][0] * 256 * K;
            gb.B2[t] = (tnrel[t] > 1) ? (WlT + (size_t)trels[t][1] * 256 * K) : gb.B1[t];
            gb.R[t] = Nn[t];
            gb.rowoff[t] = roff[t];
            gb.nsrc[t] = 1 + tnrel[t];
        }
        gb.bcum[0] = 0; gb.bcum[1] = 157; gb.bcum[2] = 548; gb.bcum[3] = 627;
        gb.outF = out; gb.outB = hb;
        gb.K = K; gb.kshift = layer ? 8 : 7; gb.outf32 = layer;
        gemm_mfma<<<651, 512, 0, stream>>>(gb);

        hipMemsetAsync(stats, 0, (size_t)4 * 512 * 4, stream);
        if (layer == 0) {
            bn_stats_all<0><<<649, 256, 0, stream>>>(hb, stats);
            bn_apply_all<0><<<2048, 256, 0, stream>>>(hb, stats, gg, be);
        } else {
            bn_stats_all<1><<<649, 256, 0, stream>>>(out, stats);
            bn_apply_all<1><<<2048, 256, 0, stream>>>(out, stats, gg, be);
        }
    }
}

// Round 8
// 774.129 us; speedup vs baseline: 6.2169x; 1.1162x over previous
//
#include <hip/hip_runtime.h>

#define EPS_BN 1e-5f

typedef short bf16x8 __attribute__((ext_vector_type(8)));
typedef float f32x4 __attribute__((ext_vector_type(4)));

__device__ __forceinline__ unsigned short f2b(float f)
{
    union { float f; unsigned int u; } c; c.f = f;
    unsigned int u = c.u + 0x7FFFu + ((c.u >> 16) & 1u);
    return (unsigned short)(u >> 16);
}
__device__ __forceinline__ float blo(unsigned int u)
{
    union { unsigned int u; float f; } c; c.u = u << 16; return c.f;
}
__device__ __forceinline__ float bhi(unsigned int u)
{
    union { unsigned int u; float f; } c; c.u = u & 0xFFFF0000u; return c.f;
}

// acc += a.lo*sel.lo + a.hi*sel.hi  (bf16 pairs, f32 accum) — 1 instr per bf16 value
__device__ __forceinline__ float dot2bf(float acc, unsigned int a, unsigned int sel)
{
    asm("v_dot2_f32_bf16 %0, %1, %2, %0" : "+v"(acc) : "v"(a), "v"(sel));
    return acc;
}

// async global->LDS, 16B per lane; LDS dest = wave-uniform base + lane*16
__device__ __forceinline__ void async_ld16(const unsigned short* g, unsigned short* l)
{
    __builtin_amdgcn_global_load_lds(
        (const __attribute__((address_space(1))) unsigned int*)g,
        (__attribute__((address_space(3))) unsigned int*)l, 16, 0, 0);
}

// relation / type index helpers (branchless compare-sums)
__device__ __forceinline__ int relof_e(int e) {
    return (e>=500000)+(e>=900000)+(e>=1050000)+(e>=1450000)+(e>=1950000)+(e>=2350000);
}
__device__ __forceinline__ int relof_n(int i) {
    return (i>=10000)+(i>=60000)+(i>=63000)+(i>=73000)+(i>=93000)+(i>=113000);
}
__device__ __forceinline__ int eoff_of(int r) {
    return r<1?0 : r<2?500000 : r<3?900000 : r<4?1050000 : r<5?1450000 : r<6?1950000 : 2350000;
}
__device__ __forceinline__ int coff_of(int r) {
    return r<1?0 : r<2?10000 : r<3?60000 : r<4?63000 : r<5?73000 : r<6?93000 : 113000;
}
__device__ __forceinline__ int typ_of(int row) { return (row>=20000)+(row>=70000)+(row>=80000); }
__device__ __forceinline__ float invR_of(int t){ return t<1?5e-5f : t<2?2e-5f : t<3?1e-4f : (1.0f/3000.0f); }

struct Graph { const int* src[7]; const int* dst[7]; };

__device__ __forceinline__ void relptrs(const Graph& g, int r, const int*& sp, const int*& dp)
{
    sp = g.src[0]; dp = g.dst[0];
    if (r==1){sp=g.src[1];dp=g.dst[1];}
    if (r==2){sp=g.src[2];dp=g.dst[2];}
    if (r==3){sp=g.src[3];dp=g.dst[3];}
    if (r==4){sp=g.src[4];dp=g.dst[4];}
    if (r==5){sp=g.src[5];dp=g.dst[5];}
    if (r==6){sp=g.src[6];dp=g.dst[6];}
}

// ---------------------------------------------------------------- degree histogram (all rels, 1 launch)
__global__ void count_all(Graph g, int* __restrict__ icnt)
{
    for (int e = blockIdx.x * blockDim.x + threadIdx.x; e < 2500000; e += gridDim.x * blockDim.x) {
        int r = relof_e(e);
        const int *sp, *dp; relptrs(g, r, sp, dp);
        int le = e - eoff_of(r);
        atomicAdd(&icnt[coff_of(r) + dp[le]], 1);
    }
}

// ---------------------------------------------------------------- 3-phase global scan
__global__ __launch_bounds__(1024)
void scan1(const int* __restrict__ icnt, int* __restrict__ scanbuf, int* __restrict__ bsums)
{
    __shared__ int lds[1024];
    int tid = threadIdx.x;
    int gid = blockIdx.x * 1024 + tid;
    int v = (gid < 163000) ? icnt[gid] : 0;
    lds[tid] = v;
    __syncthreads();
    for (int d = 1; d < 1024; d <<= 1) {
        int t = (tid >= d) ? lds[tid - d] : 0;
        __syncthreads();
        lds[tid] += t;
        __syncthreads();
    }
    scanbuf[gid] = lds[tid];                  // inclusive within block
    if (tid == 1023) bsums[blockIdx.x] = lds[1023];
}

__global__ __launch_bounds__(256)
void scan2(int* __restrict__ bsums)          // exclusive scan of 160 partials, in place
{
    __shared__ int lds[256];
    int tid = threadIdx.x;
    int v = (tid < 160) ? bsums[tid] : 0;
    lds[tid] = v;
    __syncthreads();
    for (int d = 1; d < 256; d <<= 1) {
        int t = (tid >= d) ? lds[tid - d] : 0;
        __syncthreads();
        lds[tid] += t;
        __syncthreads();
    }
    bsums[tid] = tid ? lds[tid - 1] : 0;
}

// fixup: rowptrG (global cumulative), cur (insert cursors), inv (1/max(deg,1)),
// sliceid: 8-way partition of dst space with EQUAL EDGE COUNT per slice (for fill locality)
__global__ __launch_bounds__(256)
void scan_fix(const int* __restrict__ icnt, const int* __restrict__ scanbuf,
              const int* __restrict__ bsums, int* __restrict__ rowptrG,
              int* __restrict__ cur, float* __restrict__ inv,
              unsigned char* __restrict__ sliceid)
{
    int idx = blockIdx.x * blockDim.x + threadIdx.x;
    if (idx > 163000) return;
    int G = bsums[idx >> 10] + ((idx & 1023) ? scanbuf[idx - 1] : 0);
    rowptrG[idx] = G;
    if (idx < 163000) {
        cur[idx] = G;
        inv[idx] = 1.0f / (float)max(icnt[idx], 1);
        int s = G / 312500;                    // 2.5M edges / 8 slices
        sliceid[idx] = (unsigned char)(s > 7 ? 7 : s);
    }
}

// ---------------------------------------------------------------- CSR fill, XCD-sliced
__global__ void fill_all(Graph g, const unsigned char* __restrict__ sliceid,
                         int* __restrict__ cur, int* __restrict__ csr)
{
    const int slice = blockIdx.x & 7;
    const int bper  = gridDim.x >> 3;
    const int bidx  = blockIdx.x >> 3;
    for (int e = bidx * blockDim.x + threadIdx.x; e < 2500000; e += bper * blockDim.x) {
        int r = relof_e(e);
        const int *sp, *dp; relptrs(g, r, sp, dp);
        int le = e - eoff_of(r);
        int gidx = coff_of(r) + dp[le];
        if (sliceid[gidx] == slice)
            csr[atomicAdd(&cur[gidx], 1)] = sp[le];
    }
}

// ---------------------------------------------------------------- f32 -> bf16, all 4 types in one launch
__global__ void tob16_all(const float* __restrict__ x0, const float* __restrict__ x1,
                          const float* __restrict__ x2, const float* __restrict__ x3,
                          unsigned short* __restrict__ xb)
{
    const int total = 83000 * 32;             // float4 chunks (128 f32/row)
    for (int i = blockIdx.x * blockDim.x + threadIdx.x; i < total; i += gridDim.x * blockDim.x) {
        int row = i >> 5, c4 = i & 31;
        int t = typ_of(row);
        const float* xp = (t == 0) ? x0 : (t == 1) ? x1 : (t == 2) ? x2 : x3;
        int lrow = row - (t < 1 ? 0 : t < 2 ? 20000 : t < 3 ? 70000 : 80000);
        float4 v = ((const float4*)(xp + (size_t)lrow * 128))[c4];
        uint2 o;
        o.x = (unsigned int)f2b(v.x) | ((unsigned int)f2b(v.y) << 16);
        o.y = (unsigned int)f2b(v.z) | ((unsigned int)f2b(v.w) << 16);
        ((uint2*)(xb + (size_t)row * 128))[c4] = o;
    }
}

// ---------------------------------------------------------------- fused gather-mean, all relations in one launch
// dot2-based accumulate (1 instr/value), predicated uniform body (no serial tail)
struct GatherCfg {
    const unsigned short* X[7];
    const int* rowptrG;
    const int* csr;
    const float* inv;
    unsigned short* agg;
};

template <int D>
__global__ __launch_bounds__(256)
void gather_all(GatherCfg c)
{
    constexpr int LPE = D / 8;        // lanes per edge (one uint4 = 16B each)
    constexpr int EPW = 64 / LPE;     // edges per wave concurrently (4 or 2)
    constexpr int U   = 4;            // loads in flight per lane
    int wid = (blockIdx.x * blockDim.x + threadIdx.x) >> 6;
    if (wid >= 163000) return;
    int l = threadIdx.x & 63;
    int q = l & (LPE - 1);
    int gg = l / LPE;
    int r = relof_n(wid);
    const unsigned short* X = c.X[0];
    if (r==1) X=c.X[1];
    if (r==2) X=c.X[2];
    if (r==3) X=c.X[3];
    if (r==4) X=c.X[4];
    if (r==5) X=c.X[5];
    if (r==6) X=c.X[6];
    const unsigned short* Xq = X + q * 8;
    const int* csr = c.csr;
    int beg = c.rowptrG[wid], end = c.rowptrG[wid + 1];
    float acc[8] = {0.f,0.f,0.f,0.f,0.f,0.f,0.f,0.f};
    if (beg < end) {
        const int last = end - 1;
        for (int it = beg; it < end; it += U * EPW) {
            uint4 v[U]; unsigned int sl[U];
#pragma unroll
            for (int j = 0; j < U; ++j) {
                int idx = it + j * EPW + gg;
                int e = idx < last ? idx : last;      // clamp: overhang re-reads last edge
                int s = csr[e];
                v[j]  = *(const uint4*)(Xq + (size_t)s * D);
                sl[j] = (idx <= last) ? 0x00003F80u : 0u;   // bf16 1.0 selector, 0 if masked
            }
#pragma unroll
            for (int j = 0; j < U; ++j) {
                unsigned int lo = sl[j], hi = sl[j] << 16;
                acc[0] = dot2bf(acc[0], v[j].x, lo);
                acc[1] = dot2bf(acc[1], v[j].x, hi);
                acc[2] = dot2bf(acc[2], v[j].y, lo);
                acc[3] = dot2bf(acc[3], v[j].y, hi);
                acc[4] = dot2bf(acc[4], v[j].z, lo);
                acc[5] = dot2bf(acc[5], v[j].z, hi);
                acc[6] = dot2bf(acc[6], v[j].w, lo);
                acc[7] = dot2bf(acc[7], v[j].w, hi);
            }
        }
    }
#pragma unroll
    for (int k = 0; k < 8; ++k) {
        if (LPE == 16) acc[k] += __shfl_xor(acc[k], 16);
        acc[k] += __shfl_xor(acc[k], 32);
    }
    if (l < LPE) {
        float inv = c.inv[wid];
        uint4 o;
        o.x = (unsigned int)f2b(acc[0]*inv) | ((unsigned int)f2b(acc[1]*inv) << 16);
        o.y = (unsigned int)f2b(acc[2]*inv) | ((unsigned int)f2b(acc[3]*inv) << 16);
        o.z = (unsigned int)f2b(acc[4]*inv) | ((unsigned int)f2b(acc[5]*inv) << 16);
        o.w = (unsigned int)f2b(acc[6]*inv) | ((unsigned int)f2b(acc[7]*inv) << 16);
        *(uint4*)(c.agg + (size_t)wid * D + q * 8) = o;
    }
}

// ---------------------------------------------------------------- weight prep: sum roots, transpose to [N][K] bf16
// (biases dropped: a per-column constant cancels exactly in train-mode BN's v - mu)
__global__ void wtrans_kernel(const float* __restrict__ Wr, const float* __restrict__ Wl,
                              unsigned short* __restrict__ wsumT, unsigned short* __restrict__ WlT,
                              int K)
{
    const int nrel[4]  = {2, 2, 2, 1};
    const int rl[4][2] = {{4,5},{1,6},{0,3},{2,2}};
    int per = 256 * K;
    int tot = 11 * per;
    for (int idx = blockIdx.x * blockDim.x + threadIdx.x; idx < tot;
         idx += gridDim.x * blockDim.x) {
        if (idx < 4 * per) {
            int t = idx / per, rem = idx - t * per;
            int n = rem / K, k = rem - n * K;
            float s = Wr[(size_t)rl[t][0] * per + k * 256 + n];
            if (nrel[t] > 1) s += Wr[(size_t)rl[t][1] * per + k * 256 + n];
            wsumT[idx] = f2b(s);
        } else {
            int j = idx - 4 * per;
            int r = j / per, rem = j - r * per;
            int n = rem / K, k = rem - n * K;
            WlT[j] = f2b(Wl[(size_t)r * per + k * 256 + n]);
        }
    }
}

// ---------------------------------------------------------------- fused MFMA GEMM, 128x256 tile, 8 waves (2x4),
// global_load_lds staging with pre-swizzled source (rule #21), BN-stats fused in epilogue
struct GemmBatch {
    const unsigned short* A0[4];
    const unsigned short* A1[4];
    const unsigned short* A2[4];
    const unsigned short* B0[4];
    const unsigned short* B1[4];
    const unsigned short* B2[4];
    float* outF;
    unsigned short* outB;
    float* stats;
    int R[4]; int bcum[4]; int rowoff[4]; int nsrc[4];
    int K, kshift, outf32;
};

__global__ __launch_bounds__(512, 4)
void gemm_mfma(GemmBatch g)
{
    __shared__ __align__(16) unsigned short Atile[2][128 * 32];   // 16 KB
    __shared__ __align__(16) unsigned short Btile[2][256 * 32];   // 32 KB

    const int tid = threadIdx.x;
    const int bz = blockIdx.x;
    const int t = (bz >= g.bcum[1]) + (bz >= g.bcum[2]) + (bz >= g.bcum[3]);
    const int bm = (bz - g.bcum[t]) << 7;
    const int w = tid >> 6, l = tid & 63;
    const int wr = w >> 2, wc = w & 3;          // 2x4 waves, wave tile 64 rows x 64 cols

    const int R = g.R[t];
    const int K = g.K, kshift = g.kshift, kmask = K - 1;
    const unsigned short* A0t = g.A0[t];
    const unsigned short* A1t = g.A1[t];
    const unsigned short* A2t = g.A2[t];
    const unsigned short* B0t = g.B0[t];
    const unsigned short* B1t = g.B1[t];
    const unsigned short* B2t = g.B2[t];
    const int steps = (g.nsrc[t] * K) >> 5;

    // staging geometry: lane l of wave w fills LDS row (w*16 + (l>>2)), chunk (l&3).
    // LDS[row][c] must hold global[row][c ^ swz(row)], swz(row) = (row>>1)&3 -> pre-swizzle source.
    const int rloc = tid >> 2;                                    // 0..127
    const int swz  = (((tid & 3) ^ ((tid >> 3) & 3)) << 3);       // source k-offset (elems)
    const int srowA = min(bm + rloc, R - 1);                      // clamp: garbage only feeds rows >= R
    const int wseg  = w << 9;                                     // w*512 ushorts = 1KB per wave

    auto stage = [&](int st, int buf) {
        int kglob = st << 5;
        int s  = kglob >> kshift;
        int kk = kglob & kmask;
        const unsigned short* As = (s == 0) ? A0t : (s == 1) ? A1t : A2t;
        const unsigned short* Bs = (s == 0) ? B0t : (s == 1) ? B1t : B2t;
        async_ld16(As + (size_t)srowA * K + kk + swz, &Atile[buf][wseg]);
        async_ld16(Bs + (size_t)rloc  * K + kk + swz, &Btile[buf][wseg]);
        async_ld16(Bs + (size_t)(128 + rloc) * K + kk + swz, &Btile[buf][4096 + wseg]);
    };

    f32x4 acc[4][4];
#pragma unroll
    for (int i = 0; i < 4; ++i)
#pragma unroll
        for (int j = 0; j < 4; ++j)
            acc[i][j] = (f32x4){0.f, 0.f, 0.f, 0.f};

    const int ck = l >> 4;
    const int ra = wr * 64 + (l & 15);
    const int aoff = ra * 32 + ((ck ^ ((ra >> 1) & 3)) << 3);
    const int rb = wc * 64 + (l & 15);
    const int boff = rb * 32 + ((ck ^ ((rb >> 1) & 3)) << 3);   // +16 rows keeps swz invariant

    stage(0, 0);
    __syncthreads();
    int cur = 0;
    for (int st = 0; st < steps; ++st) {
        if (st + 1 < steps) stage(st + 1, cur ^ 1);
        const unsigned short* At = Atile[cur];
        const unsigned short* Bt = Btile[cur];
        bf16x8 af[4], bfr[4];
#pragma unroll
        for (int i = 0; i < 4; ++i) {
            af[i]  = *(const bf16x8*)(At + aoff + i * 512);
            bfr[i] = *(const bf16x8*)(Bt + boff + i * 512);
        }
#pragma unroll
        for (int mi = 0; mi < 4; ++mi)
#pragma unroll
            for (int ni = 0; ni < 4; ++ni)
                acc[mi][ni] = __builtin_amdgcn_mfma_f32_16x16x32_bf16(
                    af[mi], bfr[ni], acc[mi][ni], 0, 0, 0);
        __syncthreads();     // drains next-tile global_load_lds + this tile's ds_reads
        cur ^= 1;
    }

    // epilogue: write output + per-column BN partial sums (sum, sumsq)
    const int orow0 = bm + wr * 64 + ((l >> 4) << 2);
    const int ocol0 = wc * 64 + (l & 15);
#pragma unroll
    for (int ni = 0; ni < 4; ++ni) {
        int col = ocol0 + ni * 16;
        float ps = 0.f, pq = 0.f;
#pragma unroll
        for (int mi = 0; mi < 4; ++mi) {
#pragma unroll
            for (int j = 0; j < 4; ++j) {
                int row = orow0 + mi * 16 + j;
                float v = acc[mi][ni][j];
                if (row < R) {
                    size_t o = (size_t)(g.rowoff[t] + row) * 256 + col;
                    if (g.outf32) g.outF[o] = v;
                    else          g.outB[o] = f2b(v);
                } else v = 0.f;
                ps += v; pq += v * v;
            }
        }
        ps += __shfl_xor(ps, 16); ps += __shfl_xor(ps, 32);
        pq += __shfl_xor(pq, 16); pq += __shfl_xor(pq, 32);
        if (l < 16) {
            atomicAdd(&g.stats[t * 512 + col], ps);
            atomicAdd(&g.stats[t * 512 + 256 + col], pq);
        }
    }
}

// ---------------------------------------------------------------- BatchNorm apply (train-mode) + ReLU
template <int F32>
__global__ __launch_bounds__(256)
void bn_apply_all(void* __restrict__ Hv, const float* __restrict__ stats,
                  const float* __restrict__ gg, const float* __restrict__ be)
{
    const int total4 = 83000 * 64;
    for (int i4 = blockIdx.x * blockDim.x + threadIdx.x; i4 < total4;
         i4 += gridDim.x * blockDim.x) {
        int row = i4 >> 6;
        int c4  = (i4 & 63) << 2;
        int t   = typ_of(row);
        float invR = invR_of(t);
        const float* st = stats + t * 512;
        float vin[4];
        if (F32) {
            float4 v = *(const float4*)((const float*)Hv + (size_t)row * 256 + c4);
            vin[0]=v.x; vin[1]=v.y; vin[2]=v.z; vin[3]=v.w;
        } else {
            uint2 u = *(const uint2*)((const unsigned short*)Hv + (size_t)row * 256 + c4);
            vin[0]=blo(u.x); vin[1]=bhi(u.x); vin[2]=blo(u.y); vin[3]=bhi(u.y);
        }
        float vout[4];
#pragma unroll
        for (int k = 0; k < 4; ++k) {
            int c = c4 + k;
            float mu  = st[c] * invR;
            float var = st[256 + c] * invR - mu * mu;
            float sc  = rsqrtf(var + EPS_BN) * gg[c];
            float v   = (vin[k] - mu) * sc + be[c];
            vout[k] = fmaxf(v, 0.f);
        }
        if (F32) {
            float4 o; o.x=vout[0]; o.y=vout[1]; o.z=vout[2]; o.w=vout[3];
            *(float4*)((float*)Hv + (size_t)row * 256 + c4) = o;
        } else {
            uint2 o;
            o.x = (unsigned int)f2b(vout[0]) | ((unsigned int)f2b(vout[1]) << 16);
            o.y = (unsigned int)f2b(vout[2]) | ((unsigned int)f2b(vout[3]) << 16);
            *(uint2*)((unsigned short*)Hv + (size_t)row * 256 + c4) = o;
        }
    }
}

// ---------------------------------------------------------------- host
extern "C" void kernel_launch(void* const* d_in, const int* in_sizes, int n_in,
                              void* d_out, int out_size, void* d_ws, size_t ws_size,
                              hipStream_t stream)
{
    static const int Nn[4]   = {20000, 50000, 10000, 3000};
    static const int roff[4] = {0, 20000, 70000, 80000};
    static const int rst[7]  = {0, 0, 1, 1, 2, 1, 3};
    static const int coff[7] = {0, 10000, 60000, 63000, 73000, 93000, 113000};
    static const int trels[4][2] = {{4,5},{1,6},{0,3},{2,2}};
    static const int tnrel[4]    = {2, 2, 2, 1};
    const int CNT_TOTAL = 163000;

    const float* x[4];
    for (int t = 0; t < 4; ++t) x[t] = (const float*)d_in[t];
    Graph graph;
    for (int i = 0; i < 7; ++i) {
        graph.src[i] = (const int*)d_in[4 + 2 * i];
        graph.dst[i] = (const int*)d_in[5 + 2 * i];
    }
    const float* W1l = (const float*)d_in[18];
    const float* W1r = (const float*)d_in[19];
    const float* W2l = (const float*)d_in[21];
    const float* W2r = (const float*)d_in[22];
    const float* g1  = (const float*)d_in[24];
    const float* be1 = (const float*)d_in[25];
    const float* g2  = (const float*)d_in[26];
    const float* be2 = (const float*)d_in[27];
    float* out = (float*)d_out;
    (void)n_in; (void)in_sizes; (void)out_size; (void)ws_size;

    // ---- workspace carve (~143 MB)
    char* w = (char*)d_ws;
    size_t off = 0;
    auto carve = [&](size_t bytes) -> void* {
        void* p = (void*)(w + off);
        off = (off + bytes + 255) & ~(size_t)255;
        return p;
    };
    int*   icnt    = (int*)carve((size_t)CNT_TOTAL * 4);
    int*   cur     = (int*)carve((size_t)CNT_TOTAL * 4);
    int*   rowptrG = (int*)carve((size_t)(CNT_TOTAL + 1) * 4);
    int*   csr     = (int*)carve((size_t)2500000 * 4);
    int*   scanbuf = (int*)carve((size_t)163840 * 4);
    int*   bsums   = (int*)carve((size_t)256 * 4);
    float* inv     = (float*)carve((size_t)CNT_TOTAL * 4);
    float* stats   = (float*)carve((size_t)2 * 4 * 512 * 4);   // [layer][type][sum|sumsq][256]
    unsigned char* sliceid = (unsigned char*)carve((size_t)CNT_TOTAL);
    unsigned short* wsumT1 = (unsigned short*)carve((size_t)4 * 256 * 128 * 2);
    unsigned short* WlT1   = (unsigned short*)carve((size_t)7 * 256 * 128 * 2);
    unsigned short* wsumT2 = (unsigned short*)carve((size_t)4 * 256 * 256 * 2);
    unsigned short* WlT2   = (unsigned short*)carve((size_t)7 * 256 * 256 * 2);
    unsigned short* U      = (unsigned short*)carve((size_t)163000 * 256 * 2); // union region
    unsigned short* hb     = (unsigned short*)carve((size_t)83000 * 256 * 2);
    unsigned short* xb    = U;                        // layer-1: bf16 inputs (21.25 MB)
    unsigned short* aggL1 = U + (size_t)83000 * 128;  // layer-1 agg (after xb)
    unsigned short* aggL2 = U;                        // layer-2 agg (xb dead by then)
    float* stats1 = stats;
    float* stats2 = stats + 2048;

    // ---- CSR build (globally-cumulative rowptr; shared by both layers)
    hipMemsetAsync(icnt, 0, (size_t)CNT_TOTAL * 4, stream);
    hipMemsetAsync(stats, 0, (size_t)2 * 4 * 512 * 4, stream);
    count_all<<<2048, 256, 0, stream>>>(graph, icnt);
    scan1<<<160, 1024, 0, stream>>>(icnt, scanbuf, bsums);
    scan2<<<1, 256, 0, stream>>>(bsums);
    scan_fix<<<(CNT_TOTAL + 256) / 256, 256, 0, stream>>>(icnt, scanbuf, bsums,
                                                          rowptrG, cur, inv, sliceid);
    fill_all<<<2048, 256, 0, stream>>>(graph, sliceid, cur, csr);

    // ---- x -> bf16 (one launch) + weight prep (both layers)
    tob16_all<<<2048, 256, 0, stream>>>(x[0], x[1], x[2], x[3], xb);
    wtrans_kernel<<<1024, 256, 0, stream>>>(W1r, W1l, wsumT1, WlT1, 128);
    wtrans_kernel<<<1024, 256, 0, stream>>>(W2r, W2l, wsumT2, WlT2, 256);

    for (int layer = 0; layer < 2; ++layer) {
        const int K = layer ? 256 : 128;
        const float* gg = layer ? g2  : g1;
        const float* be = layer ? be2 : be1;
        unsigned short* agg = layer ? aggL2 : aggL1;
        unsigned short* wsumT = layer ? wsumT2 : wsumT1;
        unsigned short* WlT   = layer ? WlT2   : WlT1;
        float* st = layer ? stats2 : stats1;

        GatherCfg gc;
        for (int r = 0; r < 7; ++r)
            gc.X[r] = layer ? (hb + (size_t)roff[rst[r]] * 256)
                            : (xb + (size_t)roff[rst[r]] * 128);
        gc.rowptrG = rowptrG; gc.csr = csr; gc.inv = inv; gc.agg = agg;
        if (layer == 0) gather_all<128><<<40750, 256, 0, stream>>>(gc);
        else            gather_all<256><<<40750, 256, 0, stream>>>(gc);

        GemmBatch gb;
        for (int t = 0; t < 4; ++t) {
            gb.A0[t] = layer ? (hb + (size_t)roff[t] * 256) : (xb + (size_t)roff[t] * 128);
            gb.A1[t] = agg + (size_t)coff[trels[t][0]] * K;
            gb.A2[t] = (tnrel[t] > 1) ? (agg + (size_t)coff[trels[t][1]] * K) : gb.A1[t];
            gb.B0[t] = wsumT + (size_t)t * 256 * K;
            gb.B1[t] = WlT + (size_t)trels[t][0] * 256 * K;
            gb.B2[t] = (tnrel[t] > 1) ? (WlT + (size_t)trels[t][1] * 256 * K) : gb.B1[t];
            gb.R[t] = Nn[t];
            gb.rowoff[t] = roff[t];
            gb.nsrc[t] = 1 + tnrel[t];
        }
        gb.bcum[0] = 0; gb.bcum[1] = 157; gb.bcum[2] = 548; gb.bcum[3] = 627;
        gb.outF = out; gb.outB = hb;
        gb.stats = st;
        gb.K = K; gb.kshift = layer ? 8 : 7; gb.outf32 = layer;
        gemm_mfma<<<651, 512, 0, stream>>>(gb);

        if (layer == 0) bn_apply_all<0><<<2048, 256, 0, stream>>>(hb, st, gg, be);
        else            bn_apply_all<1><<<2048, 256, 0, stream>>>(out, st, gg, be);
    }
}